// Round 9
// baseline (460.477 us; speedup 1.0000x reference)
//
#include <hip/hip_runtime.h>
#include <stdint.h>

typedef unsigned short ushort_t;
typedef unsigned int uint_t;

typedef __bf16 bf16x8 __attribute__((ext_vector_type(8)));
typedef float f32x4 __attribute__((ext_vector_type(4)));

#define DM 768
#define DFF 3072
#define NH 12
#define DH 64
#define TLEN 2048
#define BATCH 4
#define NROWS (BATCH * TLEN) /* 8192 */
#define QKVW (3 * DM)        /* 2304 */
#define STG ((size_t)NROWS * DM) /* per-type staged size: 6291456 el */

#if __has_builtin(__builtin_amdgcn_exp2f)
#define EXP2(x) __builtin_amdgcn_exp2f(x)
#else
extern "C" __device__ float __ocml_native_exp2_f32(float);
#define EXP2(x) __ocml_native_exp2_f32(x)
#endif

__device__ __forceinline__ float b2f(ushort_t u) {
  union { uint_t i; float f; } c; c.i = ((uint_t)u) << 16; return c.f;
}
__device__ __forceinline__ ushort_t f2b(float f) {
  union { float f; uint_t i; } c; c.f = f;
  uint_t i = c.i;
  return (ushort_t)((i + 0x7fffu + ((i >> 16) & 1u)) >> 16);
}

__device__ __forceinline__ void gl_lds16(const ushort_t* g, ushort_t* l) {
  __builtin_amdgcn_global_load_lds(
      (const __attribute__((address_space(1))) uint_t*)g,
      (__attribute__((address_space(3))) uint_t*)l, 16, 0, 0);
}

// gelu(x) = x * sigmoid(2c), c = 0.79788456*(x + 0.044715 x^3)
// = x / (1 + 2^{-(a x + b x^3)}), a = 2*0.79788456*log2(e), b = a*0.044715
__device__ __forceinline__ float gelu_f(float x) {
  float x2 = x * x;
  float c2n = -x * __builtin_fmaf(0.10294323f, x2, 2.3022082f);
  float t = EXP2(c2n);
  return x * __builtin_amdgcn_rcpf(1.0f + t);
}

// ---------------- dtype detect ----------------
__global__ __launch_bounds__(256) void detect_dtype(const ushort_t* __restrict__ x,
                                                    int* __restrict__ flag) {
  __shared__ int cnt[256];
  int c = 0;
  for (int i = threadIdx.x; i < 65536; i += 256)
    c += ((x[i] & 0x7F80u) == 0x7F80u) ? 1 : 0;
  cnt[threadIdx.x] = c;
  __syncthreads();
  for (int s = 128; s >= 1; s >>= 1) {
    if (threadIdx.x < s) cnt[threadIdx.x] += cnt[threadIdx.x + s];
    __syncthreads();
  }
  if (threadIdx.x == 0) flag[0] = (cnt[0] > 0) ? 1 : 0;
}

// all 8 small vectors packed into one dst buffer
__global__ __launch_bounds__(256) void cvt_smalls(
    const void* s0, const void* s1, const void* s2, const void* s3,
    const void* s4, const void* s5, const void* s6, const void* s7,
    ushort_t* __restrict__ dst, const int* __restrict__ flag) {
  int f = flag[0];
  int i = blockIdx.x * 256 + threadIdx.x;
  if (i >= 9984) return;
  const void* src; int off;
  if (i < 768)       { src = s0; off = i; }
  else if (i < 1536) { src = s1; off = i - 768; }
  else if (i < 3840) { src = s2; off = i - 1536; }
  else if (i < 4608) { src = s3; off = i - 3840; }
  else if (i < 5376) { src = s4; off = i - 4608; }
  else if (i < 6144) { src = s5; off = i - 5376; }
  else if (i < 9216) { src = s6; off = i - 6144; }
  else               { src = s7; off = i - 9216; }
  dst[i] = f ? f2b(((const float*)src)[off]) : ((const ushort_t*)src)[off];
}

// ---------------- transpose raw weight slice -> bf16 [C][R] ----------------
__global__ __launch_bounds__(256) void transpose_adapt(
    const void* __restrict__ inbase, long long inOff, ushort_t* __restrict__ out,
    int R, int C, int ldIn, const int* __restrict__ flag) {
  __shared__ alignas(16) ushort_t tile[32][33];
  int f = flag[0];
  const float* in32 = (const float*)inbase + inOff;
  const ushort_t* in16 = (const ushort_t*)inbase + inOff;
  int tc = blockIdx.x * 32, tr = blockIdx.y * 32;
  int lx = threadIdx.x & 31, ly = threadIdx.x >> 5;
#pragma unroll
  for (int i = 0; i < 32; i += 8) {
    size_t idx = (size_t)(tr + ly + i) * ldIn + tc + lx;
    tile[ly + i][lx] = f ? f2b(in32[idx]) : in16[idx];
  }
  __syncthreads();
#pragma unroll
  for (int i = 0; i < 32; i += 8)
    out[(size_t)(tc + ly + i) * R + tr + lx] = tile[lx][ly + i];
}

// ---------------- LayerNorm: one wave per 768-row. RAW reads flag dtype -------
template <bool RAW>
__global__ __launch_bounds__(256) void ln_kernel(
    const void* __restrict__ xr, const ushort_t* __restrict__ g,
    const ushort_t* __restrict__ b, ushort_t* __restrict__ out,
    const int* __restrict__ flag) {
  int row = blockIdx.x * 4 + (threadIdx.x >> 6);
  int lane = threadIdx.x & 63;
  float v[12];
  if (RAW && flag[0]) {
    const float2* xp = (const float2*)((const float*)xr + (size_t)row * DM);
#pragma unroll
    for (int j = 0; j < 6; j++) {
      float2 t = xp[lane + 64 * j];
      v[2 * j] = t.x; v[2 * j + 1] = t.y;
    }
  } else {
    const uint_t* xu = (const uint_t*)((const ushort_t*)xr + (size_t)row * DM);
#pragma unroll
    for (int j = 0; j < 6; j++) {
      uint_t wv = xu[lane + 64 * j];
      v[2 * j] = b2f((ushort_t)(wv & 0xffffu));
      v[2 * j + 1] = b2f((ushort_t)(wv >> 16));
    }
  }
  float sum = 0.f, ss = 0.f;
#pragma unroll
  for (int k = 0; k < 12; k++) { sum += v[k]; ss += v[k] * v[k]; }
#pragma unroll
  for (int off = 32; off >= 1; off >>= 1) {
    sum += __shfl_xor(sum, off, 64);
    ss += __shfl_xor(ss, off, 64);
  }
  float mu = sum * (1.f / DM);
  float var = ss * (1.f / DM) - mu * mu;
  float rs = rsqrtf(var + 1e-5f);
  uint_t* ou = (uint_t*)(out + (size_t)row * DM);
  const uint_t* gu = (const uint_t*)g;
  const uint_t* bu = (const uint_t*)b;
#pragma unroll
  for (int j = 0; j < 6; j++) {
    int idx = lane + 64 * j;
    uint_t gw = gu[idx], bw = bu[idx];
    float o0 = (v[2 * j] - mu) * rs * b2f((ushort_t)(gw & 0xffffu)) + b2f((ushort_t)(bw & 0xffffu));
    float o1 = (v[2 * j + 1] - mu) * rs * b2f((ushort_t)(gw >> 16)) + b2f((ushort_t)(bw >> 16));
    ou[idx] = (uint_t)f2b(o0) | ((uint_t)f2b(o1) << 16);
  }
}

// ---------------- GEMM: out[M,N] = A[M,K] @ BT[N,K]^T + bias ------------------
// 3-buffer counted-vmcnt pipeline: ONE raw s_barrier per K-step, loads get two
// full iterations to land. Iteration kt:
//   stage tile kt+2 -> buf (kt+2)%3   [WAR: that buf was read at kt-1; the
//                                      end-of-(kt-1) barrier (after lgkmcnt(0))
//                                      guarantees all waves done reading]
//   ds_read frags from buf kt%3      [RAW: end-of-(kt-1) vmcnt(LPS)+barrier
//                                      published tile kt residency]
//   lgkmcnt(0) -> MFMA -> vmcnt(LPS) -> barrier.
// Chunk-rotation swizzle (conflict-free, r6): phys chunk c at row r holds
// global chunk (c+(r>>1))&3; read applies inverse.
// RESMODE: 0 none, 1 internal-bf16 res, 2 raw res (flag dtype).
// OUTMODE: 0 internal bf16; 1 d_out (flag dtype, opt accumulate); 2 staged QKV
//   (q/k tiled+swizzled; V key order permuted to match attn's in-register
//    softmax A-fragments).
// BM: 128 (2x2 waves of 64x64, LDS 48KB) or 64 (2x2 waves of 32x64, LDS 36KB;
// N=768 GEMMs -> 768 blocks = 3/CU).
template <bool GELU, int RESMODE, int OUTMODE, int BM = 128>
__global__ __launch_bounds__(256) void gemm_bt(
    const ushort_t* __restrict__ A, const ushort_t* __restrict__ BT,
    const ushort_t* __restrict__ bias, const void* __restrict__ res,
    void* __restrict__ outp, int M, int N, int K, int accum,
    const int* __restrict__ flagp) {
  constexpr int MI = (BM == 128) ? 4 : 2;  // A-frags per wave
  constexpr int NI = 4;                    // B-frags per wave
  __shared__ alignas(16) ushort_t sA[3][BM * 32];
  __shared__ alignas(16) ushort_t sB[3][128 * 32];
  const int m0 = blockIdx.x * BM;
  const int n0 = blockIdx.y * 128;
  const int tid = threadIdx.x;
  const int w = tid >> 6, lane = tid & 63;
  const int quad = lane >> 4, l16 = lane & 15;
  const int wm = (w & 1) * (BM / 2);
  const int wn = (w >> 1) * 64;

  const f32x4 vz = {0.f, 0.f, 0.f, 0.f};
  f32x4 acc[MI][NI];
#pragma unroll
  for (int i = 0; i < MI; i++)
#pragma unroll
    for (int j = 0; j < NI; j++) acc[i][j] = vz;

  // staging source: row = lane>>2 within strip, phys chunk = lane&3 fetches
  // global chunk (c + (r>>1))&3  (r>>1 == (lane>>3); invariant to +16 rows)
  const int colA = (((lane & 3) + ((lane >> 3) & 3)) & 3) * 8;
  const int rowAa = w * (BM / 4) + (lane >> 2);
  const int rowBb = w * 32 + (lane >> 2);
  const ushort_t* gA = A + (size_t)(m0 + rowAa) * K + colA;
  const ushort_t* gB = BT + (size_t)(n0 + rowBb) * K + colA;

  auto stage = [&](int k0, int buf) {
    ushort_t* lA = &sA[buf][(w * (BM / 4)) * 32];
    ushort_t* lB = &sB[buf][(w * 32) * 32];
    gl_lds16(gA + k0, lA);
    if constexpr (BM == 128) gl_lds16(gA + k0 + (size_t)16 * K, lA + 16 * 32);
    gl_lds16(gB + k0, lB);
    gl_lds16(gB + k0 + (size_t)16 * K, lB + 16 * 32);
  };
  // loads per stage (per wave): BM=128 -> 4, BM=64 -> 3. asm immediates below.

  const int nk = K >> 5;  // >= 24 for all our GEMMs
  stage(0, 0);
  stage(32, 1);
  // wait own tile-0 loads (allow tile-1's LPS in flight), then all-waves barrier
  if constexpr (BM == 128) asm volatile("s_waitcnt vmcnt(4)" ::: "memory");
  else                     asm volatile("s_waitcnt vmcnt(3)" ::: "memory");
  __builtin_amdgcn_s_barrier();

  int br = 0;  // read-buffer index = kt % 3 (wave-uniform)
  for (int kt = 0; kt < nk; ++kt) {
    // 0) stage tile kt+2 into buf (kt+2)%3 == (br+2)%3 (read at kt-1; safe)
    if (kt + 2 < nk) {
      int bw = br + 2; if (bw >= 3) bw -= 3;
      stage((kt + 2) << 5, bw);
    }
    // 1) read fragments of tile kt (inverse chunk rotation)
    bf16x8 af[MI], bfr[NI];
#pragma unroll
    for (int i = 0; i < MI; i++) {
      int ra = wm + i * 16 + l16;
      af[i] = *(const bf16x8*)&sA[br][ra * 32 + ((quad + 4 - ((ra >> 1) & 3)) & 3) * 8];
    }
#pragma unroll
    for (int i = 0; i < NI; i++) {
      int rb = wn + i * 16 + l16;
      bfr[i] = *(const bf16x8*)&sB[br][rb * 32 + ((quad + 4 - ((rb >> 1) & 3)) & 3) * 8];
    }
    // 2) my LDS reads complete (needed before end-of-iter barrier: next iter's
    //    stage overwrites this buf)
    asm volatile("s_waitcnt lgkmcnt(0)" ::: "memory");
    __builtin_amdgcn_sched_barrier(0);
    // 3) MFMA on registers
#pragma unroll
    for (int mi = 0; mi < MI; mi++)
#pragma unroll
      for (int ni = 0; ni < NI; ni++)
        acc[mi][ni] = __builtin_amdgcn_mfma_f32_16x16x32_bf16(af[mi], bfr[ni], acc[mi][ni], 0, 0, 0);
    // 4) wait own tile kt+1 loads (only kt+2's may remain), 5) barrier
    if (kt + 2 < nk) {
      if constexpr (BM == 128) asm volatile("s_waitcnt vmcnt(4)" ::: "memory");
      else                     asm volatile("s_waitcnt vmcnt(3)" ::: "memory");
      __builtin_amdgcn_s_barrier();
    } else if (kt + 1 < nk) {
      asm volatile("s_waitcnt vmcnt(0)" ::: "memory");
      __builtin_amdgcn_s_barrier();
    }
    br = (br + 1 == 3) ? 0 : br + 1;
  }

  ushort_t* o16 = (ushort_t*)outp;
  float* o32 = (float*)outp;
  const int f32io = (OUTMODE == 1 || RESMODE == 2) ? flagp[0] : 0;
#pragma unroll
  for (int mi = 0; mi < MI; mi++) {
#pragma unroll
    for (int ni = 0; ni < NI; ni++) {
      int col = n0 + wn + ni * 16 + l16;
      float bs = bias ? b2f(bias[col]) : 0.0f;
#pragma unroll
      for (int r = 0; r < 4; r++) {
        int row = m0 + wm + mi * 16 + quad * 4 + r;
        size_t idx = (size_t)row * N + col;
        float v = acc[mi][ni][r] + bs;
        if (GELU) v = gelu_f(v);
        if (RESMODE == 1) v += b2f(((const ushort_t*)res)[idx]);
        if (RESMODE == 2)
          v += f32io ? ((const float*)res)[idx] : b2f(((const ushort_t*)res)[idx]);
        if (OUTMODE == 1) {
          if (accum) v += f32io ? o32[idx] : b2f(o16[idx]);
          if (f32io) o32[idx] = v; else o16[idx] = f2b(v);
        } else if (OUTMODE == 2) {
          // staged QKV write: type by col / 768
          int b = row >> 11, kt2 = (row >> 7) & 15, kl = row & 127;
          int ty = col >= 1536 ? 2 : (col >= 768 ? 1 : 0);
          int c2 = col - ty * 768;
          int hh = c2 >> 6, d = c2 & 63;
          if (ty == 0) v *= 0.18033688011112042f;  // 0.125 * log2(e) folded into Q
          size_t tb = ((size_t)(b * NH + hh) * 16 + kt2) * 8192;
          size_t sidx;
          if (ty == 2) {
            // V: key permuted to attn's in-reg-softmax A-frag order:
            // orig key within 64-blk = 16m + 4qd + r -> pos (m>>1)*32 + qd*8 + (m&1)*4 + r
            int k64 = kl & 63, m = k64 >> 4, qd = (k64 >> 2) & 3, r2 = k64 & 3;
            int pl = (kl & 0x40) | ((m >> 1) << 5) | (qd << 3) | ((m & 1) << 2) | r2;
            sidx = tb + (size_t)d * 128 + (size_t)(((pl >> 3) ^ (d & 7)) << 3) + (pl & 7);
          } else {
            // Q/K: [key][dim], 16B chunks xor-swizzled by key&7
            sidx = tb + (size_t)kl * 64 + (size_t)(((d >> 3) ^ (kl & 7)) << 3) + (d & 7);
          }
          o16[ty * STG + sidx] = f2b(v);
        } else {
          o16[idx] = f2b(v);
        }
      }
    }
  }
}

// ---------------- flash attention, software-pipelined 64-key subtiles ---------
// block per (bh, q-tile); grid.x = bh so XCD(=linear%8) sees only bh%8 => K/V
// working set 3MB/XCD fits L2. no-max softmax (Q pre-scaled): p = 2^s.
// Swapped QK^T (S^T = mfma(K,Q)): lane holds P-row values in registers ->
// softmax+pack fully in-register (exp2 + cvt_pk), NO LDS P round trip.
// V staged with matching key permutation (see gemm_bt OUTMODE=2).
__global__ __launch_bounds__(256) void attn_kernel(
    const ushort_t* __restrict__ qs, const ushort_t* __restrict__ ks,
    const ushort_t* __restrict__ vs, ushort_t* __restrict__ attnout) {
  __shared__ alignas(16) ushort_t sK[2][64 * 64];  // dbuf K subtile (Q staged here first)
  __shared__ alignas(16) ushort_t sV[2][64 * 64];  // dbuf V^T subtile
  const int bh = blockIdx.x;       // 0..47
  const int qt = blockIdx.y;       // 0..15
  const int tid = threadIdx.x;
  const int w = tid >> 6, lane = tid & 63;
  const int quad = lane >> 4, l16 = lane & 15;
  const int xsw = l16 & 7;
  const ushort_t* ktg0 = ks + (size_t)bh * 16 * 8192;
  const ushort_t* vtg0 = vs + (size_t)bh * 16 * 8192;

  // stage Q tile (16KB) into sK[0]+sK[1]
  {
    const ushort_t* qtg = qs + ((size_t)bh * 16 + qt) * 8192;
#pragma unroll
    for (int i = 0; i < 4; i++) {
      int off = (w * 4 + i) * 512;
      ushort_t* dst = (off < 4096) ? &sK[0][off] : &sK[1][off - 4096];
      gl_lds16(qtg + off + lane * 8, dst);
    }
  }
  __syncthreads();
  bf16x8 qf[2][2];
#pragma unroll
  for (int mq = 0; mq < 2; mq++) {
    int q = w * 32 + mq * 16 + l16;
    const ushort_t* sq = (q < 64) ? &sK[0][q * 64] : &sK[1][(q - 64) * 64];
#pragma unroll
    for (int c = 0; c < 2; c++)
      qf[mq][c] = *(const bf16x8*)&sq[((c * 4 + quad) ^ (q & 7)) * 8];
  }
  __syncthreads();  // all waves done extracting Q before buffers are reused

  bf16x8 onesf;
#pragma unroll
  for (int i = 0; i < 8; i++) onesf[i] = (__bf16)1.0f;

  f32x4 lsum[2];
  f32x4 oacc[2][4];
  const f32x4 vz = {0.f, 0.f, 0.f, 0.f};
#pragma unroll
  for (int mq = 0; mq < 2; mq++) {
    lsum[mq] = vz;
#pragma unroll
    for (int nd = 0; nd < 4; nd++) oacc[mq][nd] = vz;
  }

  // stage 64-key subtile j into buffer buf (per wave: 2 K-insts + 2 V-insts)
  auto stage = [&](int j, int buf) {
    const ushort_t* kg = ktg0 + (size_t)(j >> 1) * 8192 + (j & 1) * 4096;
    const ushort_t* vg = vtg0 + (size_t)(j >> 1) * 8192 + (j & 1) * 64;
#pragma unroll
    for (int i = 0; i < 2; i++) {
      int off = (w * 2 + i) * 512;
      gl_lds16(kg + off + lane * 8, &sK[buf][off]);
      // V rows: d = (w*2+i)*8 + (lane>>3), 8 chunks of this 64-key half
      gl_lds16(vg + (size_t)((w * 2 + i) * 8 + (lane >> 3)) * 128 + (lane & 7) * 8,
               &sV[buf][off]);
    }
  };

  stage(0, 0);  // preload first subtile

  for (int j = 0; j < 32; j++) {
    const int buf = j & 1;
    __syncthreads();  // implicit vmcnt(0): subtile j resident; prior reads done
    if (j < 31) stage(j + 1, 1 - buf);  // prefetch overlaps compute below

    // S^T = K Q^T (swapped): lane holds S[key=nk*16+quad*4+r][q=w*32+mq*16+l16]
    f32x4 s[2][4];
    __builtin_amdgcn_s_setprio(1);
#pragma unroll
    for (int nk = 0; nk < 4; nk++) {
      int key = nk * 16 + l16;
      bf16x8 kf0 = *(const bf16x8*)&sK[buf][key * 64 + ((quad) ^ (key & 7)) * 8];
      bf16x8 kf1 = *(const bf16x8*)&sK[buf][key * 64 + ((4 + quad) ^ (key & 7)) * 8];
#pragma unroll
      for (int mq = 0; mq < 2; mq++) {
        s[mq][nk] = __builtin_amdgcn_mfma_f32_16x16x32_bf16(kf0, qf[mq][0], vz, 0, 0, 0);
        s[mq][nk] = __builtin_amdgcn_mfma_f32_16x16x32_bf16(kf1, qf[mq][1], s[mq][nk], 0, 0, 0);
      }
    }
    __builtin_amdgcn_s_setprio(0);

    // p = 2^s, packed fully in-register into PV A-fragments.
    // frag element j: k'-slot quad*8+j <-> orig key (2c+(j>>2))*16 + 4*quad + (j&3);
    // V staging permutation matches (gemm_bt OUTMODE=2).
    bf16x8 pa[2][2];
#pragma unroll
    for (int mq = 0; mq < 2; mq++)
#pragma unroll
      for (int c = 0; c < 2; c++) {
        union { uint_t u[4]; bf16x8 v; } pk;
#pragma unroll
        for (int t = 0; t < 4; t++) {
          float lo = EXP2(s[mq][2 * c + (t >> 1)][(t & 1) * 2 + 0]);
          float hi = EXP2(s[mq][2 * c + (t >> 1)][(t & 1) * 2 + 1]);
          uint_t w32;
          asm("v_cvt_pk_bf16_f32 %0, %1, %2" : "=v"(w32) : "v"(lo), "v"(hi));
          pk.u[t] = w32;
        }
        pa[mq][c] = pk.v;
      }

    __builtin_amdgcn_s_setprio(1);
#pragma unroll
    for (int c = 0; c < 2; c++)
#pragma unroll
      for (int mq = 0; mq < 2; mq++)
        lsum[mq] = __builtin_amdgcn_mfma_f32_16x16x32_bf16(pa[mq][c], onesf, lsum[mq], 0, 0, 0);
#pragma unroll
    for (int c = 0; c < 2; c++)
#pragma unroll
      for (int nd = 0; nd < 4; nd++) {
        bf16x8 vf = *(const bf16x8*)&sV[buf][(nd * 16 + l16) * 64 + ((c * 4 + quad) ^ xsw) * 8];
#pragma unroll
        for (int mq = 0; mq < 2; mq++)
          oacc[mq][nd] = __builtin_amdgcn_mfma_f32_16x16x32_bf16(pa[mq][c], vf, oacc[mq][nd], 0, 0, 0);
      }
    __builtin_amdgcn_s_setprio(0);
  }

  // epilogue: O / l -> attnout[b*T + q][h*64 + d]
  const int b = bh / NH, h = bh - b * NH;
#pragma unroll
  for (int mq = 0; mq < 2; mq++) {
    float inv[4];
#pragma unroll
    for (int r = 0; r < 4; r++) inv[r] = __builtin_amdgcn_rcpf(lsum[mq][r]);
#pragma unroll
    for (int nd = 0; nd < 4; nd++) {
#pragma unroll
      for (int r = 0; r < 4; r++) {
        size_t row = (size_t)b * TLEN + qt * 128 + w * 32 + mq * 16 + quad * 4 + r;
        int col = h * DH + nd * 16 + l16;
        attnout[row * DM + col] = f2b(oacc[mq][nd][r] * inv[r]);
      }
    }
  }
}

// ---------------- launcher ----------------
extern "C" void kernel_launch(void* const* d_in, const int* in_sizes, int n_in,
                              void* d_out, int out_size, void* d_ws, size_t ws_size,
                              hipStream_t stream) {
  const void* x_r = d_in[0];
  const void* ln1_g_r = d_in[1];
  const void* ln1_b_r = d_in[2];
  const void* qkv_w_r = d_in[3];
  const void* qkv_b_r = d_in[4];
  const void* ao_w_r = d_in[5];
  const void* ao_b_r = d_in[6];
  const void* ln2_g_r = d_in[7];
  const void* ln2_b_r = d_in[8];
  const void* ff1_w_r = d_in[9];
  const void* ff1_b_r = d_in[10];
  const void* ff2_w_r = d_in[11];
  const void* ff2_b_r = d_in[12];

  int* flag = (int*)d_ws;
  ushort_t* base = (ushort_t*)d_ws + 128;
  const size_t RD = STG;  // 6.29M el

  const size_t elA = RD + RD + (size_t)NROWS * DFF + RD + (size_t)DM * DM + 9984;
  const bool pathA = ws_size >= elA * 2 + 4096;

  detect_dtype<<<1, 256, 0, stream>>>((const ushort_t*)x_r, flag);

  if (pathA) {
    ushort_t* x2   = base;
    ushort_t* h    = base + RD;                    // h1 then h2
    ushort_t* big  = base + 2 * RD;                // staged qkv (18.87M) then ffb (25.17M)
    ushort_t* aux  = big + (size_t)NROWS * DFF;    // wTq | attnb | wT2+wT3
    ushort_t* wTa  = aux + RD;                     // [768][768]
    ushort_t* smalls = wTa + (size_t)DM * DM;
    ushort_t* wTq = aux;
    ushort_t* attnb = aux;
    ushort_t* wT2 = aux;
    ushort_t* wT3 = aux + (size_t)DFF * DM;
    ushort_t *g1 = smalls, *b1 = smalls + 768, *qb = smalls + 1536, *ab = smalls + 3840,
             *g2 = smalls + 4608, *b2 = smalls + 5376, *f1b = smalls + 6144, *f2bb = smalls + 9216;

    cvt_smalls<<<39, 256, 0, stream>>>(ln1_g_r, ln1_b_r, qkv_b_r, ao_b_r,
                                       ln2_g_r, ln2_b_r, ff1_b_r, ff2_b_r, smalls, flag);
    ln_kernel<true><<<NROWS / 4, 256, 0, stream>>>(x_r, g1, b1, h, flag);
    transpose_adapt<<<dim3(QKVW / 32, DM / 32), 256, 0, stream>>>(qkv_w_r, 0, wTq, DM, QKVW, QKVW, flag);
    gemm_bt<false, 0, 2><<<dim3(NROWS / 128, QKVW / 128), 256, 0, stream>>>(
        h, wTq, qb, nullptr, big, NROWS, QKVW, DM, 0, flag);
    attn_kernel<<<dim3(NH * BATCH, 16), 256, 0, stream>>>(big, big + STG, big + 2 * STG, attnb);
    transpose_adapt<<<dim3(DM / 32, DM / 32), 256, 0, stream>>>(ao_w_r, 0, wTa, DM, DM, DM, flag);
    gemm_bt<false, 2, 0, 64><<<dim3(NROWS / 64, DM / 128), 256, 0, stream>>>(
        attnb, wTa, ab, x_r, x2, NROWS, DM, DM, 0, flag);
    ln_kernel<false><<<NROWS / 4, 256, 0, stream>>>(x2, g2, b2, h, flag);
    transpose_adapt<<<dim3(DFF / 32, DM / 32), 256, 0, stream>>>(ff1_w_r, 0, wT2, DM, DFF, DFF, flag);
    gemm_bt<true, 0, 0><<<dim3(NROWS / 128, DFF / 128), 256, 0, stream>>>(
        h, wT2, f1b, nullptr, big, NROWS, DFF, DM, 0, flag);
    transpose_adapt<<<dim3(DM / 32, DFF / 32), 256, 0, stream>>>(ff2_w_r, 0, wT3, DFF, DM, DM, flag);
    gemm_bt<false, 1, 1, 64><<<dim3(NROWS / 64, DM / 128), 256, 0, stream>>>(
        big, wT3, f2bb, x2, d_out, NROWS, DM, DFF, 0, flag);
  } else {
    // 55.1 MB layout; FF in two 1536-wide slices
    ushort_t* regA = base;                                   // h / attnb / h2
    ushort_t* regB = base + RD;                              // staged qkv -> [x2 | ffq]
    ushort_t* slots = regB + (size_t)NROWS * QKVW;
    ushort_t* smalls = slots + (size_t)QKVW * DM + (size_t)DM * DM;
    ushort_t* h = regA, *attnb = regA, *h2 = regA;
    ushort_t* x2 = regB;
    ushort_t* ffq = regB + RD;                               // [8192][1536]
    ushort_t* wTq = slots;
    ushort_t* wTa = slots + (size_t)QKVW * DM;
    ushort_t* wT2 = slots;                                   // [1536][768]
    ushort_t* wT3 = slots + (size_t)1536 * DM;               // [768][1536]
    ushort_t *g1 = smalls, *b1 = smalls + 768, *qb = smalls + 1536, *ab = smalls + 3840,
             *g2 = smalls + 4608, *b2 = smalls + 5376, *f1b = smalls + 6144, *f2bb = smalls + 9216;

    cvt_smalls<<<39, 256, 0, stream>>>(ln1_g_r, ln1_b_r, qkv_b_r, ao_b_r,
                                       ln2_g_r, ln2_b_r, ff1_b_r, ff2_b_r, smalls, flag);
    ln_kernel<true><<<NROWS / 4, 256, 0, stream>>>(x_r, g1, b1, h, flag);
    transpose_adapt<<<dim3(QKVW / 32, DM / 32), 256, 0, stream>>>(qkv_w_r, 0, wTq, DM, QKVW, QKVW, flag);
    gemm_bt<false, 0, 2><<<dim3(NROWS / 128, QKVW / 128), 256, 0, stream>>>(
        h, wTq, qb, nullptr, regB, NROWS, QKVW, DM, 0, flag);
    attn_kernel<<<dim3(NH * BATCH, 16), 256, 0, stream>>>(regB, regB + STG, regB + 2 * STG, attnb);
    transpose_adapt<<<dim3(DM / 32, DM / 32), 256, 0, stream>>>(ao_w_r, 0, wTa, DM, DM, DM, flag);
    gemm_bt<false, 2, 0, 64><<<dim3(NROWS / 64, DM / 128), 256, 0, stream>>>(
        attnb, wTa, ab, x_r, x2, NROWS, DM, DM, 0, flag);
    ln_kernel<false><<<NROWS / 4, 256, 0, stream>>>(x2, g2, b2, h2, flag);
    for (int q = 0; q < 2; q++) {
      transpose_adapt<<<dim3(1536 / 32, DM / 32), 256, 0, stream>>>(
          ff1_w_r, (long long)q * 1536, wT2, DM, 1536, DFF, flag);
      gemm_bt<true, 0, 0><<<dim3(NROWS / 128, 1536 / 128), 256, 0, stream>>>(
          h2, wT2, f1b + q * 1536, nullptr, ffq, NROWS, 1536, DM, 0, flag);
      transpose_adapt<<<dim3(DM / 32, 1536 / 32), 256, 0, stream>>>(
          ff2_w_r, (long long)q * 1536 * DM, wT3, 1536, DM, DM, flag);
      if (q == 0)
        gemm_bt<false, 1, 1, 64><<<dim3(NROWS / 64, DM / 128), 256, 0, stream>>>(
            ffq, wT3, f2bb, x2, d_out, NROWS, DM, 1536, 0, flag);
      else
        gemm_bt<false, 0, 1, 64><<<dim3(NROWS / 64, DM / 128), 256, 0, stream>>>(
            ffq, wT3, nullptr, nullptr, d_out, NROWS, DM, 1536, 1, flag);
    }
  }
}

// Round 10
// 422.096 us; speedup vs baseline: 1.0909x; 1.0909x over previous
//
#include <hip/hip_runtime.h>
#include <stdint.h>

typedef unsigned short ushort_t;
typedef unsigned int uint_t;

typedef __bf16 bf16x8 __attribute__((ext_vector_type(8)));
typedef float f32x4 __attribute__((ext_vector_type(4)));

#define DM 768
#define DFF 3072
#define NH 12
#define DH 64
#define TLEN 2048
#define BATCH 4
#define NROWS (BATCH * TLEN) /* 8192 */
#define QKVW (3 * DM)        /* 2304 */
#define STG ((size_t)NROWS * DM) /* per-type staged size: 6291456 el */

#if __has_builtin(__builtin_amdgcn_exp2f)
#define EXP2(x) __builtin_amdgcn_exp2f(x)
#else
extern "C" __device__ float __ocml_native_exp2_f32(float);
#define EXP2(x) __ocml_native_exp2_f32(x)
#endif

__device__ __forceinline__ float b2f(ushort_t u) {
  union { uint_t i; float f; } c; c.i = ((uint_t)u) << 16; return c.f;
}
__device__ __forceinline__ ushort_t f2b(float f) {
  union { float f; uint_t i; } c; c.f = f;
  uint_t i = c.i;
  return (ushort_t)((i + 0x7fffu + ((i >> 16) & 1u)) >> 16);
}

__device__ __forceinline__ void gl_lds16(const ushort_t* g, ushort_t* l) {
  __builtin_amdgcn_global_load_lds(
      (const __attribute__((address_space(1))) uint_t*)g,
      (__attribute__((address_space(3))) uint_t*)l, 16, 0, 0);
}

// gelu(x) = x * sigmoid(2c), c = 0.79788456*(x + 0.044715 x^3)
__device__ __forceinline__ float gelu_f(float x) {
  float x2 = x * x;
  float c2n = -x * __builtin_fmaf(0.10294323f, x2, 2.3022082f);
  float t = EXP2(c2n);
  return x * __builtin_amdgcn_rcpf(1.0f + t);
}

// ---------------- dtype detect ----------------
__global__ __launch_bounds__(256) void detect_dtype(const ushort_t* __restrict__ x,
                                                    int* __restrict__ flag) {
  __shared__ int cnt[256];
  int c = 0;
  for (int i = threadIdx.x; i < 65536; i += 256)
    c += ((x[i] & 0x7F80u) == 0x7F80u) ? 1 : 0;
  cnt[threadIdx.x] = c;
  __syncthreads();
  for (int s = 128; s >= 1; s >>= 1) {
    if (threadIdx.x < s) cnt[threadIdx.x] += cnt[threadIdx.x + s];
    __syncthreads();
  }
  if (threadIdx.x == 0) flag[0] = (cnt[0] > 0) ? 1 : 0;
}

// all 8 small vectors packed into one dst buffer
__global__ __launch_bounds__(256) void cvt_smalls(
    const void* s0, const void* s1, const void* s2, const void* s3,
    const void* s4, const void* s5, const void* s6, const void* s7,
    ushort_t* __restrict__ dst, const int* __restrict__ flag) {
  int f = flag[0];
  int i = blockIdx.x * 256 + threadIdx.x;
  if (i >= 9984) return;
  const void* src; int off;
  if (i < 768)       { src = s0; off = i; }
  else if (i < 1536) { src = s1; off = i - 768; }
  else if (i < 3840) { src = s2; off = i - 1536; }
  else if (i < 4608) { src = s3; off = i - 3840; }
  else if (i < 5376) { src = s4; off = i - 4608; }
  else if (i < 6144) { src = s5; off = i - 5376; }
  else if (i < 9216) { src = s6; off = i - 6144; }
  else               { src = s7; off = i - 9216; }
  dst[i] = f ? f2b(((const float*)src)[off]) : ((const ushort_t*)src)[off];
}

// ---------------- transpose raw weight slice -> bf16 [C][R] ----------------
__global__ __launch_bounds__(256) void transpose_adapt(
    const void* __restrict__ inbase, long long inOff, ushort_t* __restrict__ out,
    int R, int C, int ldIn, const int* __restrict__ flag) {
  __shared__ alignas(16) ushort_t tile[32][33];
  int f = flag[0];
  const float* in32 = (const float*)inbase + inOff;
  const ushort_t* in16 = (const ushort_t*)inbase + inOff;
  int tc = blockIdx.x * 32, tr = blockIdx.y * 32;
  int lx = threadIdx.x & 31, ly = threadIdx.x >> 5;
#pragma unroll
  for (int i = 0; i < 32; i += 8) {
    size_t idx = (size_t)(tr + ly + i) * ldIn + tc + lx;
    tile[ly + i][lx] = f ? f2b(in32[idx]) : in16[idx];
  }
  __syncthreads();
#pragma unroll
  for (int i = 0; i < 32; i += 8)
    out[(size_t)(tc + ly + i) * R + tr + lx] = tile[lx][ly + i];
}

// ---------------- LayerNorm: one wave per 768-row. RAW reads flag dtype -------
template <bool RAW>
__global__ __launch_bounds__(256) void ln_kernel(
    const void* __restrict__ xr, const ushort_t* __restrict__ g,
    const ushort_t* __restrict__ b, ushort_t* __restrict__ out,
    const int* __restrict__ flag) {
  int row = blockIdx.x * 4 + (threadIdx.x >> 6);
  int lane = threadIdx.x & 63;
  float v[12];
  if (RAW && flag[0]) {
    const float2* xp = (const float2*)((const float*)xr + (size_t)row * DM);
#pragma unroll
    for (int j = 0; j < 6; j++) {
      float2 t = xp[lane + 64 * j];
      v[2 * j] = t.x; v[2 * j + 1] = t.y;
    }
  } else {
    const uint_t* xu = (const uint_t*)((const ushort_t*)xr + (size_t)row * DM);
#pragma unroll
    for (int j = 0; j < 6; j++) {
      uint_t wv = xu[lane + 64 * j];
      v[2 * j] = b2f((ushort_t)(wv & 0xffffu));
      v[2 * j + 1] = b2f((ushort_t)(wv >> 16));
    }
  }
  float sum = 0.f, ss = 0.f;
#pragma unroll
  for (int k = 0; k < 12; k++) { sum += v[k]; ss += v[k] * v[k]; }
#pragma unroll
  for (int off = 32; off >= 1; off >>= 1) {
    sum += __shfl_xor(sum, off, 64);
    ss += __shfl_xor(ss, off, 64);
  }
  float mu = sum * (1.f / DM);
  float var = ss * (1.f / DM) - mu * mu;
  float rs = rsqrtf(var + 1e-5f);
  uint_t* ou = (uint_t*)(out + (size_t)row * DM);
  const uint_t* gu = (const uint_t*)g;
  const uint_t* bu = (const uint_t*)b;
#pragma unroll
  for (int j = 0; j < 6; j++) {
    int idx = lane + 64 * j;
    uint_t gw = gu[idx], bw = bu[idx];
    float o0 = (v[2 * j] - mu) * rs * b2f((ushort_t)(gw & 0xffffu)) + b2f((ushort_t)(bw & 0xffffu));
    float o1 = (v[2 * j + 1] - mu) * rs * b2f((ushort_t)(gw >> 16)) + b2f((ushort_t)(bw >> 16));
    ou[idx] = (uint_t)f2b(o0) | ((uint_t)f2b(o1) << 16);
  }
}

// ---------------- GEMM: out[M,N] = A[M,K] @ BT[N,K]^T + bias ------------------
// Round-8 proven 2-buffer counted-vmcnt pipeline (T3/T4), generalized to BK:
//   ds_read tile kt -> lgkmcnt(0) -> barrier (WAR) -> stage kt+2 -> MFMA
//   -> vmcnt(LPS) (tile kt+1 landed) -> barrier. Never vmcnt(0) mid-loop.
// Bank-conflict-free chunk rotation (applied to GLOBAL source, LDS linear):
//   BK=32: phys chunk c of row r holds global chunk (c+(r>>1))&3
//   BK=64: phys chunk c of row r holds global chunk (c+r)&7
// Read applies the inverse -> 2 lanes/bank = free.
// RESMODE: 0 none, 1 internal-bf16 res, 2 raw res (flag dtype).
// OUTMODE: 0 internal bf16; 1 d_out (flag dtype, opt accumulate); 2 staged QKV
//   (q/k tiled+swizzled; V key order permuted to match attn's in-register
//    softmax A-fragments).
// BM=128 (BK=32, LDS 32KB) for big-N GEMMs; BM=64,BK=64 (LDS 48KB, 16 MFMA и
// half the barriers per K) for N=768 GEMMs (768 blocks = 3/CU).
template <bool GELU, int RESMODE, int OUTMODE, int BM = 128, int BK = 32>
__global__ __launch_bounds__(256) void gemm_bt(
    const ushort_t* __restrict__ A, const ushort_t* __restrict__ BT,
    const ushort_t* __restrict__ bias, const void* __restrict__ res,
    void* __restrict__ outp, int M, int N, int K, int accum,
    const int* __restrict__ flagp) {
  constexpr int MI = (BM == 128) ? 4 : 2;  // A-frags per wave
  constexpr int NI = 4;                    // B-frags per wave
  constexpr int KH = BK / 32;              // MFMA K-steps per tile
  constexpr int LPS = (BM / 64 + 2) * KH;  // loads per stage per wave: 4 / 3 / 6
  __shared__ alignas(16) ushort_t sA[2][BM * BK];
  __shared__ alignas(16) ushort_t sB[2][128 * BK];
  const int m0 = blockIdx.x * BM;
  const int n0 = blockIdx.y * 128;
  const int tid = threadIdx.x;
  const int w = tid >> 6, lane = tid & 63;
  const int quad = lane >> 4, l16 = lane & 15;
  const int wm = (w & 1) * (BM / 2);
  const int wn = (w >> 1) * 64;

  const f32x4 vz = {0.f, 0.f, 0.f, 0.f};
  f32x4 acc[MI][NI];
#pragma unroll
  for (int i = 0; i < MI; i++)
#pragma unroll
    for (int j = 0; j < NI; j++) acc[i][j] = vz;

  // pre-swizzled global staging column (see header comment)
  int colA;
  const ushort_t *gA, *gB;
  if constexpr (BK == 32) {
    colA = (((lane & 3) + ((lane >> 3) & 3)) & 3) * 8;
    gA = A + (size_t)(m0 + w * (BM / 4) + (lane >> 2)) * K + colA;
    gB = BT + (size_t)(n0 + w * 32 + (lane >> 2)) * K + colA;
  } else {
    colA = (((lane & 7) + (lane >> 3)) & 7) * 8;
    gA = A + (size_t)(m0 + w * 16 + (lane >> 3)) * K + colA;
    gB = BT + (size_t)(n0 + w * 32 + (lane >> 3)) * K + colA;
  }

  auto stage = [&](int k0, int buf) {
    if constexpr (BK == 32) {
      ushort_t* lA = &sA[buf][(w * (BM / 4)) * 32];
      ushort_t* lB = &sB[buf][(w * 32) * 32];
      gl_lds16(gA + k0, lA);
      if constexpr (BM == 128) gl_lds16(gA + k0 + (size_t)16 * K, lA + 16 * 32);
      gl_lds16(gB + k0, lB);
      gl_lds16(gB + k0 + (size_t)16 * K, lB + 16 * 32);
    } else {
      ushort_t* lA = &sA[buf][(w * 16) * 64];
      ushort_t* lB = &sB[buf][(w * 32) * 64];
      gl_lds16(gA + k0, lA);
      gl_lds16(gA + k0 + (size_t)8 * K, lA + 8 * 64);
#pragma unroll
      for (int i = 0; i < 4; i++)
        gl_lds16(gB + k0 + (size_t)(8 * i) * K, lB + i * 8 * 64);
    }
  };

  auto wait_lps = [&]() {
    if constexpr (LPS == 4) asm volatile("s_waitcnt vmcnt(4)" ::: "memory");
    else if constexpr (LPS == 3) asm volatile("s_waitcnt vmcnt(3)" ::: "memory");
    else asm volatile("s_waitcnt vmcnt(6)" ::: "memory");
  };

  const int nk = K / BK;  // >= 12 for all our GEMMs
  stage(0, 0);
  stage(BK, 1);
  wait_lps();
  __builtin_amdgcn_s_barrier();

  for (int kt = 0; kt < nk; ++kt) {
    const int buf = kt & 1;
    // 1) read fragments of tile kt (inverse chunk rotation)
    bf16x8 af[KH][MI], bfr[KH][NI];
#pragma unroll
    for (int kk = 0; kk < KH; kk++) {
#pragma unroll
      for (int i = 0; i < MI; i++) {
        int ra = wm + i * 16 + l16;
        if constexpr (BK == 32)
          af[kk][i] = *(const bf16x8*)&sA[buf][ra * 32 + ((quad + 4 - ((ra >> 1) & 3)) & 3) * 8];
        else
          af[kk][i] = *(const bf16x8*)&sA[buf][ra * 64 + (((kk * 4 + quad) + 8 - (ra & 7)) & 7) * 8];
      }
#pragma unroll
      for (int i = 0; i < NI; i++) {
        int rb = wn + i * 16 + l16;
        if constexpr (BK == 32)
          bfr[kk][i] = *(const bf16x8*)&sB[buf][rb * 32 + ((quad + 4 - ((rb >> 1) & 3)) & 3) * 8];
        else
          bfr[kk][i] = *(const bf16x8*)&sB[buf][rb * 64 + (((kk * 4 + quad) + 8 - (rb & 7)) & 7) * 8];
      }
    }
    // 2) my reads complete -> WAR barrier (all waves done reading buf)
    asm volatile("s_waitcnt lgkmcnt(0)" ::: "memory");
    __builtin_amdgcn_sched_barrier(0);
    __builtin_amdgcn_s_barrier();
    // 3) stage tile kt+2 into the buffer just read
    if (kt + 2 < nk) stage((kt + 2) * BK, buf);
    // 4) MFMA on registers
#pragma unroll
    for (int kk = 0; kk < KH; kk++)
#pragma unroll
      for (int mi = 0; mi < MI; mi++)
#pragma unroll
        for (int ni = 0; ni < NI; ni++)
          acc[mi][ni] = __builtin_amdgcn_mfma_f32_16x16x32_bf16(af[kk][mi], bfr[kk][ni], acc[mi][ni], 0, 0, 0);
    // 5) wait own tile kt+1 loads (only kt+2's may remain), 6) barrier
    if (kt + 2 < nk) {
      wait_lps();
      __builtin_amdgcn_s_barrier();
    } else if (kt + 1 < nk) {
      asm volatile("s_waitcnt vmcnt(0)" ::: "memory");
      __builtin_amdgcn_s_barrier();
    }
  }

  ushort_t* o16 = (ushort_t*)outp;
  float* o32 = (float*)outp;
  const int f32io = (OUTMODE == 1 || RESMODE == 2) ? flagp[0] : 0;
#pragma unroll
  for (int mi = 0; mi < MI; mi++) {
#pragma unroll
    for (int ni = 0; ni < NI; ni++) {
      int col = n0 + wn + ni * 16 + l16;
      float bs = bias ? b2f(bias[col]) : 0.0f;
#pragma unroll
      for (int r = 0; r < 4; r++) {
        int row = m0 + wm + mi * 16 + quad * 4 + r;
        size_t idx = (size_t)row * N + col;
        float v = acc[mi][ni][r] + bs;
        if (GELU) v = gelu_f(v);
        if (RESMODE == 1) v += b2f(((const ushort_t*)res)[idx]);
        if (RESMODE == 2)
          v += f32io ? ((const float*)res)[idx] : b2f(((const ushort_t*)res)[idx]);
        if (OUTMODE == 1) {
          if (accum) v += f32io ? o32[idx] : b2f(o16[idx]);
          if (f32io) o32[idx] = v; else o16[idx] = f2b(v);
        } else if (OUTMODE == 2) {
          // staged QKV write: type by col / 768
          int b = row >> 11, kt2 = (row >> 7) & 15, kl = row & 127;
          int ty = col >= 1536 ? 2 : (col >= 768 ? 1 : 0);
          int c2 = col - ty * 768;
          int hh = c2 >> 6, d = c2 & 63;
          if (ty == 0) v *= 0.18033688011112042f;  // 0.125 * log2(e) folded into Q
          size_t tb = ((size_t)(b * NH + hh) * 16 + kt2) * 8192;
          size_t sidx;
          if (ty == 2) {
            // V: key permuted to attn's in-reg-softmax A-frag order:
            // orig key within 64-blk = 16m + 4qd + r -> pos (m>>1)*32 + qd*8 + (m&1)*4 + r
            int k64 = kl & 63, m = k64 >> 4, qd = (k64 >> 2) & 3, r2 = k64 & 3;
            int pl = (kl & 0x40) | ((m >> 1) << 5) | (qd << 3) | ((m & 1) << 2) | r2;
            sidx = tb + (size_t)d * 128 + (size_t)(((pl >> 3) ^ (d & 7)) << 3) + (pl & 7);
          } else {
            // Q/K: [key][dim], 16B chunks xor-swizzled by key&7
            sidx = tb + (size_t)kl * 64 + (size_t)(((d >> 3) ^ (kl & 7)) << 3) + (d & 7);
          }
          o16[ty * STG + sidx] = f2b(v);
        } else {
          o16[idx] = f2b(v);
        }
      }
    }
  }
}

// ---------------- flash attention, software-pipelined 64-key subtiles ---------
// block per (bh, q-tile); grid.x = bh so XCD(=linear%8) sees only bh%8 => K/V
// working set 3MB/XCD fits L2. no-max softmax (Q pre-scaled): p = 2^s.
// Swapped QK^T (S^T = mfma(K,Q)): lane holds P-row values in registers ->
// softmax+pack fully in-register (exp2 + cvt_pk), NO LDS P round trip.
// V staged with matching key permutation (see gemm_bt OUTMODE=2).
__global__ __launch_bounds__(256) void attn_kernel(
    const ushort_t* __restrict__ qs, const ushort_t* __restrict__ ks,
    const ushort_t* __restrict__ vs, ushort_t* __restrict__ attnout) {
  __shared__ alignas(16) ushort_t sK[2][64 * 64];  // dbuf K subtile (Q staged here first)
  __shared__ alignas(16) ushort_t sV[2][64 * 64];  // dbuf V^T subtile
  const int bh = blockIdx.x;       // 0..47
  const int qt = blockIdx.y;       // 0..15
  const int tid = threadIdx.x;
  const int w = tid >> 6, lane = tid & 63;
  const int quad = lane >> 4, l16 = lane & 15;
  const int xsw = l16 & 7;
  const ushort_t* ktg0 = ks + (size_t)bh * 16 * 8192;
  const ushort_t* vtg0 = vs + (size_t)bh * 16 * 8192;

  // stage Q tile (16KB) into sK[0]+sK[1]
  {
    const ushort_t* qtg = qs + ((size_t)bh * 16 + qt) * 8192;
#pragma unroll
    for (int i = 0; i < 4; i++) {
      int off = (w * 4 + i) * 512;
      ushort_t* dst = (off < 4096) ? &sK[0][off] : &sK[1][off - 4096];
      gl_lds16(qtg + off + lane * 8, dst);
    }
  }
  __syncthreads();
  bf16x8 qf[2][2];
#pragma unroll
  for (int mq = 0; mq < 2; mq++) {
    int q = w * 32 + mq * 16 + l16;
    const ushort_t* sq = (q < 64) ? &sK[0][q * 64] : &sK[1][(q - 64) * 64];
#pragma unroll
    for (int c = 0; c < 2; c++)
      qf[mq][c] = *(const bf16x8*)&sq[((c * 4 + quad) ^ (q & 7)) * 8];
  }
  __syncthreads();  // all waves done extracting Q before buffers are reused

  bf16x8 onesf;
#pragma unroll
  for (int i = 0; i < 8; i++) onesf[i] = (__bf16)1.0f;

  f32x4 lsum[2];
  f32x4 oacc[2][4];
  const f32x4 vz = {0.f, 0.f, 0.f, 0.f};
#pragma unroll
  for (int mq = 0; mq < 2; mq++) {
    lsum[mq] = vz;
#pragma unroll
    for (int nd = 0; nd < 4; nd++) oacc[mq][nd] = vz;
  }

  // stage 64-key subtile j into buffer buf (per wave: 2 K-insts + 2 V-insts)
  auto stage = [&](int j, int buf) {
    const ushort_t* kg = ktg0 + (size_t)(j >> 1) * 8192 + (j & 1) * 4096;
    const ushort_t* vg = vtg0 + (size_t)(j >> 1) * 8192 + (j & 1) * 64;
#pragma unroll
    for (int i = 0; i < 2; i++) {
      int off = (w * 2 + i) * 512;
      gl_lds16(kg + off + lane * 8, &sK[buf][off]);
      // V rows: d = (w*2+i)*8 + (lane>>3), 8 chunks of this 64-key half
      gl_lds16(vg + (size_t)((w * 2 + i) * 8 + (lane >> 3)) * 128 + (lane & 7) * 8,
               &sV[buf][off]);
    }
  };

  stage(0, 0);  // preload first subtile

  for (int j = 0; j < 32; j++) {
    const int buf = j & 1;
    __syncthreads();  // implicit vmcnt(0): subtile j resident; prior reads done
    if (j < 31) stage(j + 1, 1 - buf);  // prefetch overlaps compute below

    // S^T = K Q^T (swapped): lane holds S[key=nk*16+quad*4+r][q=w*32+mq*16+l16]
    f32x4 s[2][4];
    __builtin_amdgcn_s_setprio(1);
#pragma unroll
    for (int nk = 0; nk < 4; nk++) {
      int key = nk * 16 + l16;
      bf16x8 kf0 = *(const bf16x8*)&sK[buf][key * 64 + ((quad) ^ (key & 7)) * 8];
      bf16x8 kf1 = *(const bf16x8*)&sK[buf][key * 64 + ((4 + quad) ^ (key & 7)) * 8];
#pragma unroll
      for (int mq = 0; mq < 2; mq++) {
        s[mq][nk] = __builtin_amdgcn_mfma_f32_16x16x32_bf16(kf0, qf[mq][0], vz, 0, 0, 0);
        s[mq][nk] = __builtin_amdgcn_mfma_f32_16x16x32_bf16(kf1, qf[mq][1], s[mq][nk], 0, 0, 0);
      }
    }
    __builtin_amdgcn_s_setprio(0);

    // p = 2^s, packed fully in-register into PV A-fragments.
    // frag element j: k'-slot quad*8+j <-> orig key (2c+(j>>2))*16 + 4*quad + (j&3);
    // V staging permutation matches (gemm_bt OUTMODE=2).
    bf16x8 pa[2][2];
#pragma unroll
    for (int mq = 0; mq < 2; mq++)
#pragma unroll
      for (int c = 0; c < 2; c++) {
        union { uint_t u[4]; bf16x8 v; } pk;
#pragma unroll
        for (int t = 0; t < 4; t++) {
          float lo = EXP2(s[mq][2 * c + (t >> 1)][(t & 1) * 2 + 0]);
          float hi = EXP2(s[mq][2 * c + (t >> 1)][(t & 1) * 2 + 1]);
          uint_t w32;
          asm("v_cvt_pk_bf16_f32 %0, %1, %2" : "=v"(w32) : "v"(lo), "v"(hi));
          pk.u[t] = w32;
        }
        pa[mq][c] = pk.v;
      }

    __builtin_amdgcn_s_setprio(1);
#pragma unroll
    for (int c = 0; c < 2; c++)
#pragma unroll
      for (int mq = 0; mq < 2; mq++)
        lsum[mq] = __builtin_amdgcn_mfma_f32_16x16x32_bf16(pa[mq][c], onesf, lsum[mq], 0, 0, 0);
#pragma unroll
    for (int c = 0; c < 2; c++)
#pragma unroll
      for (int nd = 0; nd < 4; nd++) {
        bf16x8 vf = *(const bf16x8*)&sV[buf][(nd * 16 + l16) * 64 + ((c * 4 + quad) ^ xsw) * 8];
#pragma unroll
        for (int mq = 0; mq < 2; mq++)
          oacc[mq][nd] = __builtin_amdgcn_mfma_f32_16x16x32_bf16(pa[mq][c], vf, oacc[mq][nd], 0, 0, 0);
      }
    __builtin_amdgcn_s_setprio(0);
  }

  // epilogue: O / l -> attnout[b*T + q][h*64 + d]
  const int b = bh / NH, h = bh - b * NH;
#pragma unroll
  for (int mq = 0; mq < 2; mq++) {
    float inv[4];
#pragma unroll
    for (int r = 0; r < 4; r++) inv[r] = __builtin_amdgcn_rcpf(lsum[mq][r]);
#pragma unroll
    for (int nd = 0; nd < 4; nd++) {
#pragma unroll
      for (int r = 0; r < 4; r++) {
        size_t row = (size_t)b * TLEN + qt * 128 + w * 32 + mq * 16 + quad * 4 + r;
        int col = h * DH + nd * 16 + l16;
        attnout[row * DM + col] = f2b(oacc[mq][nd][r] * inv[r]);
      }
    }
  }
}

// ---------------- launcher ----------------
extern "C" void kernel_launch(void* const* d_in, const int* in_sizes, int n_in,
                              void* d_out, int out_size, void* d_ws, size_t ws_size,
                              hipStream_t stream) {
  const void* x_r = d_in[0];
  const void* ln1_g_r = d_in[1];
  const void* ln1_b_r = d_in[2];
  const void* qkv_w_r = d_in[3];
  const void* qkv_b_r = d_in[4];
  const void* ao_w_r = d_in[5];
  const void* ao_b_r = d_in[6];
  const void* ln2_g_r = d_in[7];
  const void* ln2_b_r = d_in[8];
  const void* ff1_w_r = d_in[9];
  const void* ff1_b_r = d_in[10];
  const void* ff2_w_r = d_in[11];
  const void* ff2_b_r = d_in[12];

  int* flag = (int*)d_ws;
  ushort_t* base = (ushort_t*)d_ws + 128;
  const size_t RD = STG;  // 6.29M el

  const size_t elA = RD + RD + (size_t)NROWS * DFF + RD + (size_t)DM * DM + 9984;
  const bool pathA = ws_size >= elA * 2 + 4096;

  detect_dtype<<<1, 256, 0, stream>>>((const ushort_t*)x_r, flag);

  if (pathA) {
    ushort_t* x2   = base;
    ushort_t* h    = base + RD;                    // h1 then h2
    ushort_t* big  = base + 2 * RD;                // staged qkv (18.87M) then ffb (25.17M)
    ushort_t* aux  = big + (size_t)NROWS * DFF;    // wTq | attnb | wT2+wT3
    ushort_t* wTa  = aux + RD;                     // [768][768]
    ushort_t* smalls = wTa + (size_t)DM * DM;
    ushort_t* wTq = aux;
    ushort_t* attnb = aux;
    ushort_t* wT2 = aux;
    ushort_t* wT3 = aux + (size_t)DFF * DM;
    ushort_t *g1 = smalls, *b1 = smalls + 768, *qb = smalls + 1536, *ab = smalls + 3840,
             *g2 = smalls + 4608, *b2 = smalls + 5376, *f1b = smalls + 6144, *f2bb = smalls + 9216;

    cvt_smalls<<<39, 256, 0, stream>>>(ln1_g_r, ln1_b_r, qkv_b_r, ao_b_r,
                                       ln2_g_r, ln2_b_r, ff1_b_r, ff2_b_r, smalls, flag);
    ln_kernel<true><<<NROWS / 4, 256, 0, stream>>>(x_r, g1, b1, h, flag);
    transpose_adapt<<<dim3(QKVW / 32, DM / 32), 256, 0, stream>>>(qkv_w_r, 0, wTq, DM, QKVW, QKVW, flag);
    gemm_bt<false, 0, 2><<<dim3(NROWS / 128, QKVW / 128), 256, 0, stream>>>(
        h, wTq, qb, nullptr, big, NROWS, QKVW, DM, 0, flag);
    attn_kernel<<<dim3(NH * BATCH, 16), 256, 0, stream>>>(big, big + STG, big + 2 * STG, attnb);
    transpose_adapt<<<dim3(DM / 32, DM / 32), 256, 0, stream>>>(ao_w_r, 0, wTa, DM, DM, DM, flag);
    gemm_bt<false, 2, 0, 64, 64><<<dim3(NROWS / 64, DM / 128), 256, 0, stream>>>(
        attnb, wTa, ab, x_r, x2, NROWS, DM, DM, 0, flag);
    ln_kernel<false><<<NROWS / 4, 256, 0, stream>>>(x2, g2, b2, h, flag);
    transpose_adapt<<<dim3(DFF / 32, DM / 32), 256, 0, stream>>>(ff1_w_r, 0, wT2, DM, DFF, DFF, flag);
    gemm_bt<true, 0, 0><<<dim3(NROWS / 128, DFF / 128), 256, 0, stream>>>(
        h, wT2, f1b, nullptr, big, NROWS, DFF, DM, 0, flag);
    transpose_adapt<<<dim3(DM / 32, DFF / 32), 256, 0, stream>>>(ff2_w_r, 0, wT3, DFF, DM, DM, flag);
    gemm_bt<false, 1, 1, 64, 64><<<dim3(NROWS / 64, DM / 128), 256, 0, stream>>>(
        big, wT3, f2bb, x2, d_out, NROWS, DM, DFF, 0, flag);
  } else {
    // 55.1 MB layout; FF in two 1536-wide slices
    ushort_t* regA = base;                                   // h / attnb / h2
    ushort_t* regB = base + RD;                              // staged qkv -> [x2 | ffq]
    ushort_t* slots = regB + (size_t)NROWS * QKVW;
    ushort_t* smalls = slots + (size_t)QKVW * DM + (size_t)DM * DM;
    ushort_t* h = regA, *attnb = regA, *h2 = regA;
    ushort_t* x2 = regB;
    ushort_t* ffq = regB + RD;                               // [8192][1536]
    ushort_t* wTq = slots;
    ushort_t* wTa = slots + (size_t)QKVW * DM;
    ushort_t* wT2 = slots;                                   // [1536][768]
    ushort_t* wT3 = slots + (size_t)1536 * DM;               // [768][1536]
    ushort_t *g1 = smalls, *b1 = smalls + 768, *qb = smalls + 1536, *ab = smalls + 3840,
             *g2 = smalls + 4608, *b2 = smalls + 5376, *f1b = smalls + 6144, *f2bb = smalls + 9216;

    cvt_smalls<<<39, 256, 0, stream>>>(ln1_g_r, ln1_b_r, qkv_b_r, ao_b_r,
                                       ln2_g_r, ln2_b_r, ff1_b_r, ff2_b_r, smalls, flag);
    ln_kernel<true><<<NROWS / 4, 256, 0, stream>>>(x_r, g1, b1, h, flag);
    transpose_adapt<<<dim3(QKVW / 32, DM / 32), 256, 0, stream>>>(qkv_w_r, 0, wTq, DM, QKVW, QKVW, flag);
    gemm_bt<false, 0, 2><<<dim3(NROWS / 128, QKVW / 128), 256, 0, stream>>>(
        h, wTq, qb, nullptr, regB, NROWS, QKVW, DM, 0, flag);
    attn_kernel<<<dim3(NH * BATCH, 16), 256, 0, stream>>>(regB, regB + STG, regB + 2 * STG, attnb);
    transpose_adapt<<<dim3(DM / 32, DM / 32), 256, 0, stream>>>(ao_w_r, 0, wTa, DM, DM, DM, flag);
    gemm_bt<false, 2, 0, 64, 64><<<dim3(NROWS / 64, DM / 128), 256, 0, stream>>>(
        attnb, wTa, ab, x_r, x2, NROWS, DM, DM, 0, flag);
    ln_kernel<false><<<NROWS / 4, 256, 0, stream>>>(x2, g2, b2, h2, flag);
    for (int q = 0; q < 2; q++) {
      transpose_adapt<<<dim3(1536 / 32, DM / 32), 256, 0, stream>>>(
          ff1_w_r, (long long)q * 1536, wT2, DM, 1536, DFF, flag);
      gemm_bt<true, 0, 0><<<dim3(NROWS / 128, 1536 / 128), 256, 0, stream>>>(
          h2, wT2, f1b + q * 1536, nullptr, ffq, NROWS, 1536, DM, 0, flag);
      transpose_adapt<<<dim3(DM / 32, 1536 / 32), 256, 0, stream>>>(
          ff2_w_r, (long long)q * 1536 * DM, wT3, 1536, DM, DM, flag);
      if (q == 0)
        gemm_bt<false, 1, 1, 64, 64><<<dim3(NROWS / 64, DM / 128), 256, 0, stream>>>(
            ffq, wT3, f2bb, x2, d_out, NROWS, DM, 1536, 0, flag);
      else
        gemm_bt<false, 0, 1, 64, 64><<<dim3(NROWS / 64, DM / 128), 256, 0, stream>>>(
            ffq, wT3, nullptr, nullptr, d_out, NROWS, DM, 1536, 1, flag);
    }
  }
}

// Round 11
// 413.837 us; speedup vs baseline: 1.1127x; 1.0200x over previous
//
#include <hip/hip_runtime.h>
#include <stdint.h>

typedef unsigned short ushort_t;
typedef unsigned int uint_t;

typedef __bf16 bf16x8 __attribute__((ext_vector_type(8)));
typedef float f32x4 __attribute__((ext_vector_type(4)));

#define DM 768
#define DFF 3072
#define NH 12
#define DH 64
#define TLEN 2048
#define BATCH 4
#define NROWS (BATCH * TLEN) /* 8192 */
#define QKVW (3 * DM)        /* 2304 */
#define STG ((size_t)NROWS * DM) /* per-type staged size: 6291456 el */

#if __has_builtin(__builtin_amdgcn_exp2f)
#define EXP2(x) __builtin_amdgcn_exp2f(x)
#else
extern "C" __device__ float __ocml_native_exp2_f32(float);
#define EXP2(x) __ocml_native_exp2_f32(x)
#endif

__device__ __forceinline__ float b2f(ushort_t u) {
  union { uint_t i; float f; } c; c.i = ((uint_t)u) << 16; return c.f;
}
__device__ __forceinline__ ushort_t f2b(float f) {
  union { float f; uint_t i; } c; c.f = f;
  uint_t i = c.i;
  return (ushort_t)((i + 0x7fffu + ((i >> 16) & 1u)) >> 16);
}

__device__ __forceinline__ void gl_lds16(const ushort_t* g, ushort_t* l) {
  __builtin_amdgcn_global_load_lds(
      (const __attribute__((address_space(1))) uint_t*)g,
      (__attribute__((address_space(3))) uint_t*)l, 16, 0, 0);
}

// gelu(x) = x * sigmoid(2c), c = 0.79788456*(x + 0.044715 x^3)
__device__ __forceinline__ float gelu_f(float x) {
  float x2 = x * x;
  float c2n = -x * __builtin_fmaf(0.10294323f, x2, 2.3022082f);
  float t = EXP2(c2n);
  return x * __builtin_amdgcn_rcpf(1.0f + t);
}

// ---------------- dtype detect ----------------
__global__ __launch_bounds__(256) void detect_dtype(const ushort_t* __restrict__ x,
                                                    int* __restrict__ flag) {
  __shared__ int cnt[256];
  int c = 0;
  for (int i = threadIdx.x; i < 65536; i += 256)
    c += ((x[i] & 0x7F80u) == 0x7F80u) ? 1 : 0;
  cnt[threadIdx.x] = c;
  __syncthreads();
  for (int s = 128; s >= 1; s >>= 1) {
    if (threadIdx.x < s) cnt[threadIdx.x] += cnt[threadIdx.x + s];
    __syncthreads();
  }
  if (threadIdx.x == 0) flag[0] = (cnt[0] > 0) ? 1 : 0;
}

// all 8 small vectors packed into one dst buffer
__global__ __launch_bounds__(256) void cvt_smalls(
    const void* s0, const void* s1, const void* s2, const void* s3,
    const void* s4, const void* s5, const void* s6, const void* s7,
    ushort_t* __restrict__ dst, const int* __restrict__ flag) {
  int f = flag[0];
  int i = blockIdx.x * 256 + threadIdx.x;
  if (i >= 9984) return;
  const void* src; int off;
  if (i < 768)       { src = s0; off = i; }
  else if (i < 1536) { src = s1; off = i - 768; }
  else if (i < 3840) { src = s2; off = i - 1536; }
  else if (i < 4608) { src = s3; off = i - 3840; }
  else if (i < 5376) { src = s4; off = i - 4608; }
  else if (i < 6144) { src = s5; off = i - 5376; }
  else if (i < 9216) { src = s6; off = i - 6144; }
  else               { src = s7; off = i - 9216; }
  dst[i] = f ? f2b(((const float*)src)[off]) : ((const ushort_t*)src)[off];
}

// ---------------- transpose raw weight slice -> bf16 [C][R] ----------------
__global__ __launch_bounds__(256) void transpose_adapt(
    const void* __restrict__ inbase, long long inOff, ushort_t* __restrict__ out,
    int R, int C, int ldIn, const int* __restrict__ flag) {
  __shared__ alignas(16) ushort_t tile[32][33];
  int f = flag[0];
  const float* in32 = (const float*)inbase + inOff;
  const ushort_t* in16 = (const ushort_t*)inbase + inOff;
  int tc = blockIdx.x * 32, tr = blockIdx.y * 32;
  int lx = threadIdx.x & 31, ly = threadIdx.x >> 5;
#pragma unroll
  for (int i = 0; i < 32; i += 8) {
    size_t idx = (size_t)(tr + ly + i) * ldIn + tc + lx;
    tile[ly + i][lx] = f ? f2b(in32[idx]) : in16[idx];
  }
  __syncthreads();
#pragma unroll
  for (int i = 0; i < 32; i += 8)
    out[(size_t)(tc + ly + i) * R + tr + lx] = tile[lx][ly + i];
}

// ---------------- LayerNorm: one wave per 768-row. RAW reads flag dtype -------
template <bool RAW>
__global__ __launch_bounds__(256) void ln_kernel(
    const void* __restrict__ xr, const ushort_t* __restrict__ g,
    const ushort_t* __restrict__ b, ushort_t* __restrict__ out,
    const int* __restrict__ flag) {
  int row = blockIdx.x * 4 + (threadIdx.x >> 6);
  int lane = threadIdx.x & 63;
  float v[12];
  if (RAW && flag[0]) {
    const float2* xp = (const float2*)((const float*)xr + (size_t)row * DM);
#pragma unroll
    for (int j = 0; j < 6; j++) {
      float2 t = xp[lane + 64 * j];
      v[2 * j] = t.x; v[2 * j + 1] = t.y;
    }
  } else {
    const uint_t* xu = (const uint_t*)((const ushort_t*)xr + (size_t)row * DM);
#pragma unroll
    for (int j = 0; j < 6; j++) {
      uint_t wv = xu[lane + 64 * j];
      v[2 * j] = b2f((ushort_t)(wv & 0xffffu));
      v[2 * j + 1] = b2f((ushort_t)(wv >> 16));
    }
  }
  float sum = 0.f, ss = 0.f;
#pragma unroll
  for (int k = 0; k < 12; k++) { sum += v[k]; ss += v[k] * v[k]; }
#pragma unroll
  for (int off = 32; off >= 1; off >>= 1) {
    sum += __shfl_xor(sum, off, 64);
    ss += __shfl_xor(ss, off, 64);
  }
  float mu = sum * (1.f / DM);
  float var = ss * (1.f / DM) - mu * mu;
  float rs = rsqrtf(var + 1e-5f);
  uint_t* ou = (uint_t*)(out + (size_t)row * DM);
  const uint_t* gu = (const uint_t*)g;
  const uint_t* bu = (const uint_t*)b;
#pragma unroll
  for (int j = 0; j < 6; j++) {
    int idx = lane + 64 * j;
    uint_t gw = gu[idx], bw = bu[idx];
    float o0 = (v[2 * j] - mu) * rs * b2f((ushort_t)(gw & 0xffffu)) + b2f((ushort_t)(bw & 0xffffu));
    float o1 = (v[2 * j + 1] - mu) * rs * b2f((ushort_t)(gw >> 16)) + b2f((ushort_t)(bw >> 16));
    ou[idx] = (uint_t)f2b(o0) | ((uint_t)f2b(o1) << 16);
  }
}

// ---------------- GEMM: out[M,N] = A[M,K] @ BT[N,K]^T + bias ------------------
// Round-8 proven 2-buffer counted-vmcnt pipeline (T3/T4), generalized to BK:
//   ds_read tile kt -> lgkmcnt(0) -> barrier (WAR) -> stage kt+2 -> MFMA
//   -> vmcnt(LPS) (tile kt+1 landed) -> barrier. Never vmcnt(0) mid-loop.
// Bank-conflict-free chunk rotation (applied to GLOBAL source, LDS linear):
//   BK=32: phys chunk c of row r holds global chunk (c+(r>>1))&3
//   BK=64: phys chunk c of row r holds global chunk (c+r)&7
// Read applies the inverse -> 2 lanes/bank = free.
// RESMODE: 0 none, 1 internal-bf16 res, 2 raw res (flag dtype).
// OUTMODE: 0 internal bf16; 1 d_out (flag dtype, opt accumulate); 2 staged QKV
//   (q/k tiled+swizzled; V key order permuted to match attn's in-register
//    softmax A-fragments).
// Config: BM=64,BK=64 (LDS 48KB, 3 blk/CU, 12-48 K-steps) now used for ALL
// square-ish GEMMs (QKV/AO/FF1/FF2) — r10 proved it beats BM=128/BK=32 in the
// latency-bound regime. BM=128/BK=32 retained as template option.
template <bool GELU, int RESMODE, int OUTMODE, int BM = 128, int BK = 32>
__global__ __launch_bounds__(256) void gemm_bt(
    const ushort_t* __restrict__ A, const ushort_t* __restrict__ BT,
    const ushort_t* __restrict__ bias, const void* __restrict__ res,
    void* __restrict__ outp, int M, int N, int K, int accum,
    const int* __restrict__ flagp) {
  constexpr int MI = (BM == 128) ? 4 : 2;  // A-frags per wave
  constexpr int NI = 4;                    // B-frags per wave
  constexpr int KH = BK / 32;              // MFMA K-steps per tile
  constexpr int LPS = (BM / 64 + 2) * KH;  // loads per stage per wave: 4 / 3 / 6
  __shared__ alignas(16) ushort_t sA[2][BM * BK];
  __shared__ alignas(16) ushort_t sB[2][128 * BK];
  const int m0 = blockIdx.x * BM;
  const int n0 = blockIdx.y * 128;
  const int tid = threadIdx.x;
  const int w = tid >> 6, lane = tid & 63;
  const int quad = lane >> 4, l16 = lane & 15;
  const int wm = (w & 1) * (BM / 2);
  const int wn = (w >> 1) * 64;

  const f32x4 vz = {0.f, 0.f, 0.f, 0.f};
  f32x4 acc[MI][NI];
#pragma unroll
  for (int i = 0; i < MI; i++)
#pragma unroll
    for (int j = 0; j < NI; j++) acc[i][j] = vz;

  // pre-swizzled global staging column (see header comment)
  int colA;
  const ushort_t *gA, *gB;
  if constexpr (BK == 32) {
    colA = (((lane & 3) + ((lane >> 3) & 3)) & 3) * 8;
    gA = A + (size_t)(m0 + w * (BM / 4) + (lane >> 2)) * K + colA;
    gB = BT + (size_t)(n0 + w * 32 + (lane >> 2)) * K + colA;
  } else {
    colA = (((lane & 7) + (lane >> 3)) & 7) * 8;
    gA = A + (size_t)(m0 + w * 16 + (lane >> 3)) * K + colA;
    gB = BT + (size_t)(n0 + w * 32 + (lane >> 3)) * K + colA;
  }

  auto stage = [&](int k0, int buf) {
    if constexpr (BK == 32) {
      ushort_t* lA = &sA[buf][(w * (BM / 4)) * 32];
      ushort_t* lB = &sB[buf][(w * 32) * 32];
      gl_lds16(gA + k0, lA);
      if constexpr (BM == 128) gl_lds16(gA + k0 + (size_t)16 * K, lA + 16 * 32);
      gl_lds16(gB + k0, lB);
      gl_lds16(gB + k0 + (size_t)16 * K, lB + 16 * 32);
    } else {
      ushort_t* lA = &sA[buf][(w * 16) * 64];
      ushort_t* lB = &sB[buf][(w * 32) * 64];
      gl_lds16(gA + k0, lA);
      gl_lds16(gA + k0 + (size_t)8 * K, lA + 8 * 64);
#pragma unroll
      for (int i = 0; i < 4; i++)
        gl_lds16(gB + k0 + (size_t)(8 * i) * K, lB + i * 8 * 64);
    }
  };

  auto wait_lps = [&]() {
    if constexpr (LPS == 4) asm volatile("s_waitcnt vmcnt(4)" ::: "memory");
    else if constexpr (LPS == 3) asm volatile("s_waitcnt vmcnt(3)" ::: "memory");
    else asm volatile("s_waitcnt vmcnt(6)" ::: "memory");
  };

  const int nk = K / BK;  // >= 12 for all our GEMMs
  stage(0, 0);
  stage(BK, 1);
  wait_lps();
  __builtin_amdgcn_s_barrier();

  for (int kt = 0; kt < nk; ++kt) {
    const int buf = kt & 1;
    // 1) read fragments of tile kt (inverse chunk rotation)
    bf16x8 af[KH][MI], bfr[KH][NI];
#pragma unroll
    for (int kk = 0; kk < KH; kk++) {
#pragma unroll
      for (int i = 0; i < MI; i++) {
        int ra = wm + i * 16 + l16;
        if constexpr (BK == 32)
          af[kk][i] = *(const bf16x8*)&sA[buf][ra * 32 + ((quad + 4 - ((ra >> 1) & 3)) & 3) * 8];
        else
          af[kk][i] = *(const bf16x8*)&sA[buf][ra * 64 + (((kk * 4 + quad) + 8 - (ra & 7)) & 7) * 8];
      }
#pragma unroll
      for (int i = 0; i < NI; i++) {
        int rb = wn + i * 16 + l16;
        if constexpr (BK == 32)
          bfr[kk][i] = *(const bf16x8*)&sB[buf][rb * 32 + ((quad + 4 - ((rb >> 1) & 3)) & 3) * 8];
        else
          bfr[kk][i] = *(const bf16x8*)&sB[buf][rb * 64 + (((kk * 4 + quad) + 8 - (rb & 7)) & 7) * 8];
      }
    }
    // 2) my reads complete -> WAR barrier (all waves done reading buf)
    asm volatile("s_waitcnt lgkmcnt(0)" ::: "memory");
    __builtin_amdgcn_sched_barrier(0);
    __builtin_amdgcn_s_barrier();
    // 3) stage tile kt+2 into the buffer just read
    if (kt + 2 < nk) stage((kt + 2) * BK, buf);
    // 4) MFMA on registers
#pragma unroll
    for (int kk = 0; kk < KH; kk++)
#pragma unroll
      for (int mi = 0; mi < MI; mi++)
#pragma unroll
        for (int ni = 0; ni < NI; ni++)
          acc[mi][ni] = __builtin_amdgcn_mfma_f32_16x16x32_bf16(af[kk][mi], bfr[kk][ni], acc[mi][ni], 0, 0, 0);
    // 5) wait own tile kt+1 loads (only kt+2's may remain), 6) barrier
    if (kt + 2 < nk) {
      wait_lps();
      __builtin_amdgcn_s_barrier();
    } else if (kt + 1 < nk) {
      asm volatile("s_waitcnt vmcnt(0)" ::: "memory");
      __builtin_amdgcn_s_barrier();
    }
  }

  ushort_t* o16 = (ushort_t*)outp;
  float* o32 = (float*)outp;
  const int f32io = (OUTMODE == 1 || RESMODE == 2) ? flagp[0] : 0;
#pragma unroll
  for (int mi = 0; mi < MI; mi++) {
#pragma unroll
    for (int ni = 0; ni < NI; ni++) {
      int col = n0 + wn + ni * 16 + l16;
      float bs = bias ? b2f(bias[col]) : 0.0f;
#pragma unroll
      for (int r = 0; r < 4; r++) {
        int row = m0 + wm + mi * 16 + quad * 4 + r;
        size_t idx = (size_t)row * N + col;
        float v = acc[mi][ni][r] + bs;
        if (GELU) v = gelu_f(v);
        if (RESMODE == 1) v += b2f(((const ushort_t*)res)[idx]);
        if (RESMODE == 2)
          v += f32io ? ((const float*)res)[idx] : b2f(((const ushort_t*)res)[idx]);
        if (OUTMODE == 1) {
          if (accum) v += f32io ? o32[idx] : b2f(o16[idx]);
          if (f32io) o32[idx] = v; else o16[idx] = f2b(v);
        } else if (OUTMODE == 2) {
          // staged QKV write: type by col / 768
          int b = row >> 11, kt2 = (row >> 7) & 15, kl = row & 127;
          int ty = col >= 1536 ? 2 : (col >= 768 ? 1 : 0);
          int c2 = col - ty * 768;
          int hh = c2 >> 6, d = c2 & 63;
          if (ty == 0) v *= 0.18033688011112042f;  // 0.125 * log2(e) folded into Q
          size_t tb = ((size_t)(b * NH + hh) * 16 + kt2) * 8192;
          size_t sidx;
          if (ty == 2) {
            // V: key permuted to attn's in-reg-softmax A-frag order:
            // orig key within 64-blk = 16m + 4qd + r -> pos (m>>1)*32 + qd*8 + (m&1)*4 + r
            int k64 = kl & 63, m = k64 >> 4, qd = (k64 >> 2) & 3, r2 = k64 & 3;
            int pl = (kl & 0x40) | ((m >> 1) << 5) | (qd << 3) | ((m & 1) << 2) | r2;
            sidx = tb + (size_t)d * 128 + (size_t)(((pl >> 3) ^ (d & 7)) << 3) + (pl & 7);
          } else {
            // Q/K: [key][dim], 16B chunks xor-swizzled by key&7
            sidx = tb + (size_t)kl * 64 + (size_t)(((d >> 3) ^ (kl & 7)) << 3) + (d & 7);
          }
          o16[ty * STG + sidx] = f2b(v);
        } else {
          o16[idx] = f2b(v);
        }
      }
    }
  }
}

// ---------------- flash attention, software-pipelined 64-key subtiles ---------
// block per (bh, q-tile); grid.x = bh so XCD(=linear%8) sees only bh%8 => K/V
// working set 3MB/XCD fits L2. no-max softmax (Q pre-scaled): p = 2^s.
// Swapped QK^T (S^T = mfma(K,Q)): lane holds P-row values in registers ->
// softmax+pack fully in-register (exp2 + cvt_pk), NO LDS P round trip.
// V staged with matching key permutation (see gemm_bt OUTMODE=2).
__global__ __launch_bounds__(256) void attn_kernel(
    const ushort_t* __restrict__ qs, const ushort_t* __restrict__ ks,
    const ushort_t* __restrict__ vs, ushort_t* __restrict__ attnout) {
  __shared__ alignas(16) ushort_t sK[2][64 * 64];  // dbuf K subtile (Q staged here first)
  __shared__ alignas(16) ushort_t sV[2][64 * 64];  // dbuf V^T subtile
  const int bh = blockIdx.x;       // 0..47
  const int qt = blockIdx.y;       // 0..15
  const int tid = threadIdx.x;
  const int w = tid >> 6, lane = tid & 63;
  const int quad = lane >> 4, l16 = lane & 15;
  const int xsw = l16 & 7;
  const ushort_t* ktg0 = ks + (size_t)bh * 16 * 8192;
  const ushort_t* vtg0 = vs + (size_t)bh * 16 * 8192;

  // stage Q tile (16KB) into sK[0]+sK[1]
  {
    const ushort_t* qtg = qs + ((size_t)bh * 16 + qt) * 8192;
#pragma unroll
    for (int i = 0; i < 4; i++) {
      int off = (w * 4 + i) * 512;
      ushort_t* dst = (off < 4096) ? &sK[0][off] : &sK[1][off - 4096];
      gl_lds16(qtg + off + lane * 8, dst);
    }
  }
  __syncthreads();
  bf16x8 qf[2][2];
#pragma unroll
  for (int mq = 0; mq < 2; mq++) {
    int q = w * 32 + mq * 16 + l16;
    const ushort_t* sq = (q < 64) ? &sK[0][q * 64] : &sK[1][(q - 64) * 64];
#pragma unroll
    for (int c = 0; c < 2; c++)
      qf[mq][c] = *(const bf16x8*)&sq[((c * 4 + quad) ^ (q & 7)) * 8];
  }
  __syncthreads();  // all waves done extracting Q before buffers are reused

  bf16x8 onesf;
#pragma unroll
  for (int i = 0; i < 8; i++) onesf[i] = (__bf16)1.0f;

  f32x4 lsum[2];
  f32x4 oacc[2][4];
  const f32x4 vz = {0.f, 0.f, 0.f, 0.f};
#pragma unroll
  for (int mq = 0; mq < 2; mq++) {
    lsum[mq] = vz;
#pragma unroll
    for (int nd = 0; nd < 4; nd++) oacc[mq][nd] = vz;
  }

  // stage 64-key subtile j into buffer buf (per wave: 2 K-insts + 2 V-insts)
  auto stage = [&](int j, int buf) {
    const ushort_t* kg = ktg0 + (size_t)(j >> 1) * 8192 + (j & 1) * 4096;
    const ushort_t* vg = vtg0 + (size_t)(j >> 1) * 8192 + (j & 1) * 64;
#pragma unroll
    for (int i = 0; i < 2; i++) {
      int off = (w * 2 + i) * 512;
      gl_lds16(kg + off + lane * 8, &sK[buf][off]);
      // V rows: d = (w*2+i)*8 + (lane>>3), 8 chunks of this 64-key half
      gl_lds16(vg + (size_t)((w * 2 + i) * 8 + (lane >> 3)) * 128 + (lane & 7) * 8,
               &sV[buf][off]);
    }
  };

  stage(0, 0);  // preload first subtile

  for (int j = 0; j < 32; j++) {
    const int buf = j & 1;
    __syncthreads();  // implicit vmcnt(0): subtile j resident; prior reads done
    if (j < 31) stage(j + 1, 1 - buf);  // prefetch overlaps compute below

    // S^T = K Q^T (swapped): lane holds S[key=nk*16+quad*4+r][q=w*32+mq*16+l16]
    f32x4 s[2][4];
    __builtin_amdgcn_s_setprio(1);
#pragma unroll
    for (int nk = 0; nk < 4; nk++) {
      int key = nk * 16 + l16;
      bf16x8 kf0 = *(const bf16x8*)&sK[buf][key * 64 + ((quad) ^ (key & 7)) * 8];
      bf16x8 kf1 = *(const bf16x8*)&sK[buf][key * 64 + ((4 + quad) ^ (key & 7)) * 8];
#pragma unroll
      for (int mq = 0; mq < 2; mq++) {
        s[mq][nk] = __builtin_amdgcn_mfma_f32_16x16x32_bf16(kf0, qf[mq][0], vz, 0, 0, 0);
        s[mq][nk] = __builtin_amdgcn_mfma_f32_16x16x32_bf16(kf1, qf[mq][1], s[mq][nk], 0, 0, 0);
      }
    }
    __builtin_amdgcn_s_setprio(0);

    // p = 2^s, packed fully in-register into PV A-fragments.
    // frag element j: k'-slot quad*8+j <-> orig key (2c+(j>>2))*16 + 4*quad + (j&3);
    // V staging permutation matches (gemm_bt OUTMODE=2).
    bf16x8 pa[2][2];
#pragma unroll
    for (int mq = 0; mq < 2; mq++)
#pragma unroll
      for (int c = 0; c < 2; c++) {
        union { uint_t u[4]; bf16x8 v; } pk;
#pragma unroll
        for (int t = 0; t < 4; t++) {
          float lo = EXP2(s[mq][2 * c + (t >> 1)][(t & 1) * 2 + 0]);
          float hi = EXP2(s[mq][2 * c + (t >> 1)][(t & 1) * 2 + 1]);
          uint_t w32;
          asm("v_cvt_pk_bf16_f32 %0, %1, %2" : "=v"(w32) : "v"(lo), "v"(hi));
          pk.u[t] = w32;
        }
        pa[mq][c] = pk.v;
      }

    __builtin_amdgcn_s_setprio(1);
#pragma unroll
    for (int c = 0; c < 2; c++)
#pragma unroll
      for (int mq = 0; mq < 2; mq++)
        lsum[mq] = __builtin_amdgcn_mfma_f32_16x16x32_bf16(pa[mq][c], onesf, lsum[mq], 0, 0, 0);
#pragma unroll
    for (int c = 0; c < 2; c++)
#pragma unroll
      for (int nd = 0; nd < 4; nd++) {
        bf16x8 vf = *(const bf16x8*)&sV[buf][(nd * 16 + l16) * 64 + ((c * 4 + quad) ^ xsw) * 8];
#pragma unroll
        for (int mq = 0; mq < 2; mq++)
          oacc[mq][nd] = __builtin_amdgcn_mfma_f32_16x16x32_bf16(pa[mq][c], vf, oacc[mq][nd], 0, 0, 0);
      }
    __builtin_amdgcn_s_setprio(0);
  }

  // epilogue: O / l -> attnout[b*T + q][h*64 + d]
  const int b = bh / NH, h = bh - b * NH;
#pragma unroll
  for (int mq = 0; mq < 2; mq++) {
    float inv[4];
#pragma unroll
    for (int r = 0; r < 4; r++) inv[r] = __builtin_amdgcn_rcpf(lsum[mq][r]);
#pragma unroll
    for (int nd = 0; nd < 4; nd++) {
#pragma unroll
      for (int r = 0; r < 4; r++) {
        size_t row = (size_t)b * TLEN + qt * 128 + w * 32 + mq * 16 + quad * 4 + r;
        int col = h * DH + nd * 16 + l16;
        attnout[row * DM + col] = f2b(oacc[mq][nd][r] * inv[r]);
      }
    }
  }
}

// ---------------- launcher ----------------
extern "C" void kernel_launch(void* const* d_in, const int* in_sizes, int n_in,
                              void* d_out, int out_size, void* d_ws, size_t ws_size,
                              hipStream_t stream) {
  const void* x_r = d_in[0];
  const void* ln1_g_r = d_in[1];
  const void* ln1_b_r = d_in[2];
  const void* qkv_w_r = d_in[3];
  const void* qkv_b_r = d_in[4];
  const void* ao_w_r = d_in[5];
  const void* ao_b_r = d_in[6];
  const void* ln2_g_r = d_in[7];
  const void* ln2_b_r = d_in[8];
  const void* ff1_w_r = d_in[9];
  const void* ff1_b_r = d_in[10];
  const void* ff2_w_r = d_in[11];
  const void* ff2_b_r = d_in[12];

  int* flag = (int*)d_ws;
  ushort_t* base = (ushort_t*)d_ws + 128;
  const size_t RD = STG;  // 6.29M el

  const size_t elA = RD + RD + (size_t)NROWS * DFF + RD + (size_t)DM * DM + 9984;
  const bool pathA = ws_size >= elA * 2 + 4096;

  detect_dtype<<<1, 256, 0, stream>>>((const ushort_t*)x_r, flag);

  if (pathA) {
    ushort_t* x2   = base;
    ushort_t* h    = base + RD;                    // h1 then h2
    ushort_t* big  = base + 2 * RD;                // staged qkv (18.87M) then ffb (25.17M)
    ushort_t* aux  = big + (size_t)NROWS * DFF;    // wTq | attnb | wT2+wT3
    ushort_t* wTa  = aux + RD;                     // [768][768]
    ushort_t* smalls = wTa + (size_t)DM * DM;
    ushort_t* wTq = aux;
    ushort_t* attnb = aux;
    ushort_t* wT2 = aux;
    ushort_t* wT3 = aux + (size_t)DFF * DM;
    ushort_t *g1 = smalls, *b1 = smalls + 768, *qb = smalls + 1536, *ab = smalls + 3840,
             *g2 = smalls + 4608, *b2 = smalls + 5376, *f1b = smalls + 6144, *f2bb = smalls + 9216;

    cvt_smalls<<<39, 256, 0, stream>>>(ln1_g_r, ln1_b_r, qkv_b_r, ao_b_r,
                                       ln2_g_r, ln2_b_r, ff1_b_r, ff2_b_r, smalls, flag);
    ln_kernel<true><<<NROWS / 4, 256, 0, stream>>>(x_r, g1, b1, h, flag);
    transpose_adapt<<<dim3(QKVW / 32, DM / 32), 256, 0, stream>>>(qkv_w_r, 0, wTq, DM, QKVW, QKVW, flag);
    gemm_bt<false, 0, 2, 64, 64><<<dim3(NROWS / 64, QKVW / 128), 256, 0, stream>>>(
        h, wTq, qb, nullptr, big, NROWS, QKVW, DM, 0, flag);
    attn_kernel<<<dim3(NH * BATCH, 16), 256, 0, stream>>>(big, big + STG, big + 2 * STG, attnb);
    transpose_adapt<<<dim3(DM / 32, DM / 32), 256, 0, stream>>>(ao_w_r, 0, wTa, DM, DM, DM, flag);
    gemm_bt<false, 2, 0, 64, 64><<<dim3(NROWS / 64, DM / 128), 256, 0, stream>>>(
        attnb, wTa, ab, x_r, x2, NROWS, DM, DM, 0, flag);
    ln_kernel<false><<<NROWS / 4, 256, 0, stream>>>(x2, g2, b2, h, flag);
    transpose_adapt<<<dim3(DFF / 32, DM / 32), 256, 0, stream>>>(ff1_w_r, 0, wT2, DM, DFF, DFF, flag);
    gemm_bt<true, 0, 0, 64, 64><<<dim3(NROWS / 64, DFF / 128), 256, 0, stream>>>(
        h, wT2, f1b, nullptr, big, NROWS, DFF, DM, 0, flag);
    transpose_adapt<<<dim3(DM / 32, DFF / 32), 256, 0, stream>>>(ff2_w_r, 0, wT3, DFF, DM, DM, flag);
    gemm_bt<false, 1, 1, 64, 64><<<dim3(NROWS / 64, DM / 128), 256, 0, stream>>>(
        big, wT3, f2bb, x2, d_out, NROWS, DM, DFF, 0, flag);
  } else {
    // 55.1 MB layout; FF in two 1536-wide slices
    ushort_t* regA = base;                                   // h / attnb / h2
    ushort_t* regB = base + RD;                              // staged qkv -> [x2 | ffq]
    ushort_t* slots = regB + (size_t)NROWS * QKVW;
    ushort_t* smalls = slots + (size_t)QKVW * DM + (size_t)DM * DM;
    ushort_t* h = regA, *attnb = regA, *h2 = regA;
    ushort_t* x2 = regB;
    ushort_t* ffq = regB + RD;                               // [8192][1536]
    ushort_t* wTq = slots;
    ushort_t* wTa = slots + (size_t)QKVW * DM;
    ushort_t* wT2 = slots;                                   // [1536][768]
    ushort_t* wT3 = slots + (size_t)1536 * DM;               // [768][1536]
    ushort_t *g1 = smalls, *b1 = smalls + 768, *qb = smalls + 1536, *ab = smalls + 3840,
             *g2 = smalls + 4608, *b2 = smalls + 5376, *f1b = smalls + 6144, *f2bb = smalls + 9216;

    cvt_smalls<<<39, 256, 0, stream>>>(ln1_g_r, ln1_b_r, qkv_b_r, ao_b_r,
                                       ln2_g_r, ln2_b_r, ff1_b_r, ff2_b_r, smalls, flag);
    ln_kernel<true><<<NROWS / 4, 256, 0, stream>>>(x_r, g1, b1, h, flag);
    transpose_adapt<<<dim3(QKVW / 32, DM / 32), 256, 0, stream>>>(qkv_w_r, 0, wTq, DM, QKVW, QKVW, flag);
    gemm_bt<false, 0, 2, 64, 64><<<dim3(NROWS / 64, QKVW / 128), 256, 0, stream>>>(
        h, wTq, qb, nullptr, regB, NROWS, QKVW, DM, 0, flag);
    attn_kernel<<<dim3(NH * BATCH, 16), 256, 0, stream>>>(regB, regB + STG, regB + 2 * STG, attnb);
    transpose_adapt<<<dim3(DM / 32, DM / 32), 256, 0, stream>>>(ao_w_r, 0, wTa, DM, DM, DM, flag);
    gemm_bt<false, 2, 0, 64, 64><<<dim3(NROWS / 64, DM / 128), 256, 0, stream>>>(
        attnb, wTa, ab, x_r, x2, NROWS, DM, DM, 0, flag);
    ln_kernel<false><<<NROWS / 4, 256, 0, stream>>>(x2, g2, b2, h2, flag);
    for (int q = 0; q < 2; q++) {
      transpose_adapt<<<dim3(1536 / 32, DM / 32), 256, 0, stream>>>(
          ff1_w_r, (long long)q * 1536, wT2, DM, 1536, DFF, flag);
      gemm_bt<true, 0, 0, 64, 64><<<dim3(NROWS / 64, 1536 / 128), 256, 0, stream>>>(
          h2, wT2, f1b + q * 1536, nullptr, ffq, NROWS, 1536, DM, 0, flag);
      transpose_adapt<<<dim3(DM / 32, 1536 / 32), 256, 0, stream>>>(
          ff2_w_r, (long long)q * 1536 * DM, wT3, 1536, DM, DM, flag);
      if (q == 0)
        gemm_bt<false, 1, 1, 64, 64><<<dim3(NROWS / 64, DM / 128), 256, 0, stream>>>(
            ffq, wT3, f2bb, x2, d_out, NROWS, DM, 1536, 0, flag);
      else
        gemm_bt<false, 0, 1, 64, 64><<<dim3(NROWS / 64, DM / 128), 256, 0, stream>>>(
            ffq, wT3, nullptr, nullptr, d_out, NROWS, DM, 1536, 1, flag);
    }
  }
}

// Round 12
// 412.335 us; speedup vs baseline: 1.1168x; 1.0036x over previous
//
#include <hip/hip_runtime.h>
#include <stdint.h>

typedef unsigned short ushort_t;
typedef unsigned int uint_t;

typedef __bf16 bf16x8 __attribute__((ext_vector_type(8)));
typedef float f32x4 __attribute__((ext_vector_type(4)));

#define DM 768
#define DFF 3072
#define NH 12
#define DH 64
#define TLEN 2048
#define BATCH 4
#define NROWS (BATCH * TLEN) /* 8192 */
#define QKVW (3 * DM)        /* 2304 */
#define STG ((size_t)NROWS * DM) /* per-type staged size: 6291456 el */

#if __has_builtin(__builtin_amdgcn_exp2f)
#define EXP2(x) __builtin_amdgcn_exp2f(x)
#else
extern "C" __device__ float __ocml_native_exp2_f32(float);
#define EXP2(x) __ocml_native_exp2_f32(x)
#endif

__device__ __forceinline__ float b2f(ushort_t u) {
  union { uint_t i; float f; } c; c.i = ((uint_t)u) << 16; return c.f;
}
__device__ __forceinline__ ushort_t f2b(float f) {
  union { float f; uint_t i; } c; c.f = f;
  uint_t i = c.i;
  return (ushort_t)((i + 0x7fffu + ((i >> 16) & 1u)) >> 16);
}

__device__ __forceinline__ void gl_lds16(const ushort_t* g, ushort_t* l) {
  __builtin_amdgcn_global_load_lds(
      (const __attribute__((address_space(1))) uint_t*)g,
      (__attribute__((address_space(3))) uint_t*)l, 16, 0, 0);
}

// gelu(x) = x * sigmoid(2c), c = 0.79788456*(x + 0.044715 x^3)
__device__ __forceinline__ float gelu_f(float x) {
  float x2 = x * x;
  float c2n = -x * __builtin_fmaf(0.10294323f, x2, 2.3022082f);
  float t = EXP2(c2n);
  return x * __builtin_amdgcn_rcpf(1.0f + t);
}

// ---------------- dtype detect ----------------
__global__ __launch_bounds__(256) void detect_dtype(const ushort_t* __restrict__ x,
                                                    int* __restrict__ flag) {
  __shared__ int cnt[256];
  int c = 0;
  for (int i = threadIdx.x; i < 65536; i += 256)
    c += ((x[i] & 0x7F80u) == 0x7F80u) ? 1 : 0;
  cnt[threadIdx.x] = c;
  __syncthreads();
  for (int s = 128; s >= 1; s >>= 1) {
    if (threadIdx.x < s) cnt[threadIdx.x] += cnt[threadIdx.x + s];
    __syncthreads();
  }
  if (threadIdx.x == 0) flag[0] = (cnt[0] > 0) ? 1 : 0;
}

// all 8 small vectors packed into one dst buffer
__global__ __launch_bounds__(256) void cvt_smalls(
    const void* s0, const void* s1, const void* s2, const void* s3,
    const void* s4, const void* s5, const void* s6, const void* s7,
    ushort_t* __restrict__ dst, const int* __restrict__ flag) {
  int f = flag[0];
  int i = blockIdx.x * 256 + threadIdx.x;
  if (i >= 9984) return;
  const void* src; int off;
  if (i < 768)       { src = s0; off = i; }
  else if (i < 1536) { src = s1; off = i - 768; }
  else if (i < 3840) { src = s2; off = i - 1536; }
  else if (i < 4608) { src = s3; off = i - 3840; }
  else if (i < 5376) { src = s4; off = i - 4608; }
  else if (i < 6144) { src = s5; off = i - 5376; }
  else if (i < 9216) { src = s6; off = i - 6144; }
  else               { src = s7; off = i - 9216; }
  dst[i] = f ? f2b(((const float*)src)[off]) : ((const ushort_t*)src)[off];
}

// ---------------- transpose raw weight slice -> bf16 [C][R] ----------------
__global__ __launch_bounds__(256) void transpose_adapt(
    const void* __restrict__ inbase, long long inOff, ushort_t* __restrict__ out,
    int R, int C, int ldIn, const int* __restrict__ flag) {
  __shared__ alignas(16) ushort_t tile[32][33];
  int f = flag[0];
  const float* in32 = (const float*)inbase + inOff;
  const ushort_t* in16 = (const ushort_t*)inbase + inOff;
  int tc = blockIdx.x * 32, tr = blockIdx.y * 32;
  int lx = threadIdx.x & 31, ly = threadIdx.x >> 5;
#pragma unroll
  for (int i = 0; i < 32; i += 8) {
    size_t idx = (size_t)(tr + ly + i) * ldIn + tc + lx;
    tile[ly + i][lx] = f ? f2b(in32[idx]) : in16[idx];
  }
  __syncthreads();
#pragma unroll
  for (int i = 0; i < 32; i += 8)
    out[(size_t)(tc + ly + i) * R + tr + lx] = tile[lx][ly + i];
}

// ---------------- LayerNorm: one wave per 768-row. RAW reads flag dtype -------
template <bool RAW>
__global__ __launch_bounds__(256) void ln_kernel(
    const void* __restrict__ xr, const ushort_t* __restrict__ g,
    const ushort_t* __restrict__ b, ushort_t* __restrict__ out,
    const int* __restrict__ flag) {
  int row = blockIdx.x * 4 + (threadIdx.x >> 6);
  int lane = threadIdx.x & 63;
  float v[12];
  if (RAW && flag[0]) {
    const float2* xp = (const float2*)((const float*)xr + (size_t)row * DM);
#pragma unroll
    for (int j = 0; j < 6; j++) {
      float2 t = xp[lane + 64 * j];
      v[2 * j] = t.x; v[2 * j + 1] = t.y;
    }
  } else {
    const uint_t* xu = (const uint_t*)((const ushort_t*)xr + (size_t)row * DM);
#pragma unroll
    for (int j = 0; j < 6; j++) {
      uint_t wv = xu[lane + 64 * j];
      v[2 * j] = b2f((ushort_t)(wv & 0xffffu));
      v[2 * j + 1] = b2f((ushort_t)(wv >> 16));
    }
  }
  float sum = 0.f, ss = 0.f;
#pragma unroll
  for (int k = 0; k < 12; k++) { sum += v[k]; ss += v[k] * v[k]; }
#pragma unroll
  for (int off = 32; off >= 1; off >>= 1) {
    sum += __shfl_xor(sum, off, 64);
    ss += __shfl_xor(ss, off, 64);
  }
  float mu = sum * (1.f / DM);
  float var = ss * (1.f / DM) - mu * mu;
  float rs = rsqrtf(var + 1e-5f);
  uint_t* ou = (uint_t*)(out + (size_t)row * DM);
  const uint_t* gu = (const uint_t*)g;
  const uint_t* bu = (const uint_t*)b;
#pragma unroll
  for (int j = 0; j < 6; j++) {
    int idx = lane + 64 * j;
    uint_t gw = gu[idx], bw = bu[idx];
    float o0 = (v[2 * j] - mu) * rs * b2f((ushort_t)(gw & 0xffffu)) + b2f((ushort_t)(bw & 0xffffu));
    float o1 = (v[2 * j + 1] - mu) * rs * b2f((ushort_t)(gw >> 16)) + b2f((ushort_t)(bw >> 16));
    ou[idx] = (uint_t)f2b(o0) | ((uint_t)f2b(o1) << 16);
  }
}

// ---------------- GEMM: out[M,N] = A[M,K] @ BT[N,K]^T + bias ------------------
// Round-8 proven 2-buffer counted-vmcnt pipeline (T3/T4), generalized to BK:
//   ds_read tile kt -> lgkmcnt(0) -> barrier (WAR) -> stage kt+2 -> MFMA
//   -> vmcnt(LPS) (tile kt+1 landed) -> barrier. Never vmcnt(0) mid-loop.
// Bank-conflict-free chunk rotation (applied to GLOBAL source, LDS linear):
//   BK=32: phys chunk c of row r holds global chunk (c+(r>>1))&3
//   BK=64: phys chunk c of row r holds global chunk (c+r)&7
// Read applies the inverse -> 2 lanes/bank = free.
// Epilogue: loops reordered (mi, r outer / ni inner) with row-invariants and
// col-invariant arrays hoisted — strength-reduces the OUTMODE=2 scatter math.
// RESMODE: 0 none, 1 internal-bf16 res, 2 raw res (flag dtype).
// OUTMODE: 0 internal bf16; 1 d_out (flag dtype, opt accumulate); 2 staged QKV.
// Config: BM=64,BK=64 (LDS 48KB, 3 blk/CU) for all GEMMs (r10/r11 verified).
template <bool GELU, int RESMODE, int OUTMODE, int BM = 128, int BK = 32>
__global__ __launch_bounds__(256) void gemm_bt(
    const ushort_t* __restrict__ A, const ushort_t* __restrict__ BT,
    const ushort_t* __restrict__ bias, const void* __restrict__ res,
    void* __restrict__ outp, int M, int N, int K, int accum,
    const int* __restrict__ flagp) {
  constexpr int MI = (BM == 128) ? 4 : 2;  // A-frags per wave
  constexpr int NI = 4;                    // B-frags per wave
  constexpr int KH = BK / 32;              // MFMA K-steps per tile
  constexpr int LPS = (BM / 64 + 2) * KH;  // loads per stage per wave: 4 / 3 / 6
  __shared__ alignas(16) ushort_t sA[2][BM * BK];
  __shared__ alignas(16) ushort_t sB[2][128 * BK];
  const int m0 = blockIdx.x * BM;
  const int n0 = blockIdx.y * 128;
  const int tid = threadIdx.x;
  const int w = tid >> 6, lane = tid & 63;
  const int quad = lane >> 4, l16 = lane & 15;
  const int wm = (w & 1) * (BM / 2);
  const int wn = (w >> 1) * 64;

  const f32x4 vz = {0.f, 0.f, 0.f, 0.f};
  f32x4 acc[MI][NI];
#pragma unroll
  for (int i = 0; i < MI; i++)
#pragma unroll
    for (int j = 0; j < NI; j++) acc[i][j] = vz;

  // pre-swizzled global staging column (see header comment)
  int colA;
  const ushort_t *gA, *gB;
  if constexpr (BK == 32) {
    colA = (((lane & 3) + ((lane >> 3) & 3)) & 3) * 8;
    gA = A + (size_t)(m0 + w * (BM / 4) + (lane >> 2)) * K + colA;
    gB = BT + (size_t)(n0 + w * 32 + (lane >> 2)) * K + colA;
  } else {
    colA = (((lane & 7) + (lane >> 3)) & 7) * 8;
    gA = A + (size_t)(m0 + w * 16 + (lane >> 3)) * K + colA;
    gB = BT + (size_t)(n0 + w * 32 + (lane >> 3)) * K + colA;
  }

  auto stage = [&](int k0, int buf) {
    if constexpr (BK == 32) {
      ushort_t* lA = &sA[buf][(w * (BM / 4)) * 32];
      ushort_t* lB = &sB[buf][(w * 32) * 32];
      gl_lds16(gA + k0, lA);
      if constexpr (BM == 128) gl_lds16(gA + k0 + (size_t)16 * K, lA + 16 * 32);
      gl_lds16(gB + k0, lB);
      gl_lds16(gB + k0 + (size_t)16 * K, lB + 16 * 32);
    } else {
      ushort_t* lA = &sA[buf][(w * 16) * 64];
      ushort_t* lB = &sB[buf][(w * 32) * 64];
      gl_lds16(gA + k0, lA);
      gl_lds16(gA + k0 + (size_t)8 * K, lA + 8 * 64);
#pragma unroll
      for (int i = 0; i < 4; i++)
        gl_lds16(gB + k0 + (size_t)(8 * i) * K, lB + i * 8 * 64);
    }
  };

  auto wait_lps = [&]() {
    if constexpr (LPS == 4) asm volatile("s_waitcnt vmcnt(4)" ::: "memory");
    else if constexpr (LPS == 3) asm volatile("s_waitcnt vmcnt(3)" ::: "memory");
    else asm volatile("s_waitcnt vmcnt(6)" ::: "memory");
  };

  const int nk = K / BK;  // >= 12 for all our GEMMs
  stage(0, 0);
  stage(BK, 1);
  wait_lps();
  __builtin_amdgcn_s_barrier();

  for (int kt = 0; kt < nk; ++kt) {
    const int buf = kt & 1;
    // 1) read fragments of tile kt (inverse chunk rotation)
    bf16x8 af[KH][MI], bfr[KH][NI];
#pragma unroll
    for (int kk = 0; kk < KH; kk++) {
#pragma unroll
      for (int i = 0; i < MI; i++) {
        int ra = wm + i * 16 + l16;
        if constexpr (BK == 32)
          af[kk][i] = *(const bf16x8*)&sA[buf][ra * 32 + ((quad + 4 - ((ra >> 1) & 3)) & 3) * 8];
        else
          af[kk][i] = *(const bf16x8*)&sA[buf][ra * 64 + (((kk * 4 + quad) + 8 - (ra & 7)) & 7) * 8];
      }
#pragma unroll
      for (int i = 0; i < NI; i++) {
        int rb = wn + i * 16 + l16;
        if constexpr (BK == 32)
          bfr[kk][i] = *(const bf16x8*)&sB[buf][rb * 32 + ((quad + 4 - ((rb >> 1) & 3)) & 3) * 8];
        else
          bfr[kk][i] = *(const bf16x8*)&sB[buf][rb * 64 + (((kk * 4 + quad) + 8 - (rb & 7)) & 7) * 8];
      }
    }
    // 2) my reads complete -> WAR barrier (all waves done reading buf)
    asm volatile("s_waitcnt lgkmcnt(0)" ::: "memory");
    __builtin_amdgcn_sched_barrier(0);
    __builtin_amdgcn_s_barrier();
    // 3) stage tile kt+2 into the buffer just read
    if (kt + 2 < nk) stage((kt + 2) * BK, buf);
    // 4) MFMA on registers
#pragma unroll
    for (int kk = 0; kk < KH; kk++)
#pragma unroll
      for (int mi = 0; mi < MI; mi++)
#pragma unroll
        for (int ni = 0; ni < NI; ni++)
          acc[mi][ni] = __builtin_amdgcn_mfma_f32_16x16x32_bf16(af[kk][mi], bfr[kk][ni], acc[mi][ni], 0, 0, 0);
    // 5) wait own tile kt+1 loads (only kt+2's may remain), 6) barrier
    if (kt + 2 < nk) {
      wait_lps();
      __builtin_amdgcn_s_barrier();
    } else if (kt + 1 < nk) {
      asm volatile("s_waitcnt vmcnt(0)" ::: "memory");
      __builtin_amdgcn_s_barrier();
    }
  }

  ushort_t* o16 = (ushort_t*)outp;
  float* o32 = (float*)outp;
  const int f32io = (OUTMODE == 1 || RESMODE == 2) ? flagp[0] : 0;
  // col-invariant preloads (per ni)
  float bsv[NI];
  int tyv[NI], hhv[NI], d7v[NI], d3v[NI], dv[NI];
#pragma unroll
  for (int ni = 0; ni < NI; ni++) {
    int col = n0 + wn + ni * 16 + l16;
    bsv[ni] = bias ? b2f(bias[col]) : 0.0f;
    if (OUTMODE == 2) {
      int ty = col >= 1536 ? 2 : (col >= 768 ? 1 : 0);
      int c2 = col - ty * 768;
      tyv[ni] = ty; hhv[ni] = c2 >> 6;
      dv[ni] = c2 & 63; d7v[ni] = c2 & 7; d3v[ni] = (c2 & 63) >> 3;
    }
  }
#pragma unroll
  for (int mi = 0; mi < MI; mi++) {
#pragma unroll
    for (int r = 0; r < 4; r++) {
      int row = m0 + wm + mi * 16 + quad * 4 + r;
      // row-invariants for OUTMODE==2
      size_t rowb = 0; int kl = 0, klsw = 0, pl = 0;
      if (OUTMODE == 2) {
        int b = row >> 11, kt2 = (row >> 7) & 15;
        kl = row & 127;
        rowb = ((size_t)(b * NH) * 16 + kt2) * 8192;  // + hh*131072 per col
        klsw = kl & 7;
        int k64 = kl & 63, m = k64 >> 4, qd = (k64 >> 2) & 3, r2 = k64 & 3;
        pl = (kl & 0x40) | ((m >> 1) << 5) | (qd << 3) | ((m & 1) << 2) | r2;
      }
#pragma unroll
      for (int ni = 0; ni < NI; ni++) {
        int col = n0 + wn + ni * 16 + l16;
        size_t idx = (size_t)row * N + col;
        float v = acc[mi][ni][r] + bsv[ni];
        if (GELU) v = gelu_f(v);
        if (RESMODE == 1) v += b2f(((const ushort_t*)res)[idx]);
        if (RESMODE == 2)
          v += f32io ? ((const float*)res)[idx] : b2f(((const ushort_t*)res)[idx]);
        if (OUTMODE == 1) {
          if (accum) v += f32io ? o32[idx] : b2f(o16[idx]);
          if (f32io) o32[idx] = v; else o16[idx] = f2b(v);
        } else if (OUTMODE == 2) {
          size_t tb = rowb + (size_t)hhv[ni] * 131072;
          size_t sidx;
          if (tyv[ni] == 2) {
            sidx = tb + (size_t)dv[ni] * 128 + (size_t)(((pl >> 3) ^ d7v[ni]) << 3) + (pl & 7);
          } else {
            if (tyv[ni] == 0) v *= 0.18033688011112042f;  // 0.125*log2(e) into Q
            sidx = tb + (size_t)kl * 64 + (size_t)((d3v[ni] ^ klsw) << 3) + d7v[ni];
          }
          o16[(size_t)tyv[ni] * STG + sidx] = f2b(v);
        } else {
          o16[idx] = f2b(v);
        }
      }
    }
  }
}

// ---------------- flash attention, software-pipelined 64-key subtiles ---------
// block per (bh, q-tile); grid.x = bh so XCD(=linear%8) sees only bh%8 => K/V
// working set 3MB/XCD fits L2. no-max softmax (Q pre-scaled): p = 2^s.
// Swapped QK^T (S^T = mfma(K,Q)): lane holds P-row values in registers ->
// softmax+pack fully in-register (exp2 + cvt_pk), NO LDS P round trip.
// V staged with matching key permutation (see gemm_bt OUTMODE=2).
// j-loop unrolled x2 so buf is compile-time -> all LDS addresses fold to
// immediate offsets (kernel is issue-bound: MfmaUtil+VALUBusy = 92%).
__global__ __launch_bounds__(256) void attn_kernel(
    const ushort_t* __restrict__ qs, const ushort_t* __restrict__ ks,
    const ushort_t* __restrict__ vs, ushort_t* __restrict__ attnout) {
  __shared__ alignas(16) ushort_t sK[2][64 * 64];  // dbuf K subtile (Q staged here first)
  __shared__ alignas(16) ushort_t sV[2][64 * 64];  // dbuf V^T subtile
  const int bh = blockIdx.x;       // 0..47
  const int qt = blockIdx.y;       // 0..15
  const int tid = threadIdx.x;
  const int w = tid >> 6, lane = tid & 63;
  const int quad = lane >> 4, l16 = lane & 15;
  const int xsw = l16 & 7;
  const ushort_t* ktg0 = ks + (size_t)bh * 16 * 8192;
  const ushort_t* vtg0 = vs + (size_t)bh * 16 * 8192;

  // stage Q tile (16KB) into sK[0]+sK[1]
  {
    const ushort_t* qtg = qs + ((size_t)bh * 16 + qt) * 8192;
#pragma unroll
    for (int i = 0; i < 4; i++) {
      int off = (w * 4 + i) * 512;
      ushort_t* dst = (off < 4096) ? &sK[0][off] : &sK[1][off - 4096];
      gl_lds16(qtg + off + lane * 8, dst);
    }
  }
  __syncthreads();
  bf16x8 qf[2][2];
#pragma unroll
  for (int mq = 0; mq < 2; mq++) {
    int q = w * 32 + mq * 16 + l16;
    const ushort_t* sq = (q < 64) ? &sK[0][q * 64] : &sK[1][(q - 64) * 64];
#pragma unroll
    for (int c = 0; c < 2; c++)
      qf[mq][c] = *(const bf16x8*)&sq[((c * 4 + quad) ^ (q & 7)) * 8];
  }
  __syncthreads();  // all waves done extracting Q before buffers are reused

  bf16x8 onesf;
#pragma unroll
  for (int i = 0; i < 8; i++) onesf[i] = (__bf16)1.0f;

  f32x4 lsum[2];
  f32x4 oacc[2][4];
  const f32x4 vz = {0.f, 0.f, 0.f, 0.f};
#pragma unroll
  for (int mq = 0; mq < 2; mq++) {
    lsum[mq] = vz;
#pragma unroll
    for (int nd = 0; nd < 4; nd++) oacc[mq][nd] = vz;
  }

  // stage 64-key subtile j into buffer buf (per wave: 2 K-insts + 2 V-insts)
  auto stage = [&](int j, int buf) {
    const ushort_t* kg = ktg0 + (size_t)(j >> 1) * 8192 + (j & 1) * 4096;
    const ushort_t* vg = vtg0 + (size_t)(j >> 1) * 8192 + (j & 1) * 64;
#pragma unroll
    for (int i = 0; i < 2; i++) {
      int off = (w * 2 + i) * 512;
      gl_lds16(kg + off + lane * 8, &sK[buf][off]);
      // V rows: d = (w*2+i)*8 + (lane>>3), 8 chunks of this 64-key half
      gl_lds16(vg + (size_t)((w * 2 + i) * 8 + (lane >> 3)) * 128 + (lane & 7) * 8,
               &sV[buf][off]);
    }
  };

  stage(0, 0);  // preload first subtile

#pragma unroll 2
  for (int j = 0; j < 32; j++) {
    const int buf = j & 1;
    __syncthreads();  // implicit vmcnt(0): subtile j resident; prior reads done
    if (j < 31) stage(j + 1, 1 - buf);  // prefetch overlaps compute below

    // S^T = K Q^T (swapped): lane holds S[key=nk*16+quad*4+r][q=w*32+mq*16+l16]
    f32x4 s[2][4];
    __builtin_amdgcn_s_setprio(1);
#pragma unroll
    for (int nk = 0; nk < 4; nk++) {
      int key = nk * 16 + l16;
      bf16x8 kf0 = *(const bf16x8*)&sK[buf][key * 64 + ((quad) ^ (key & 7)) * 8];
      bf16x8 kf1 = *(const bf16x8*)&sK[buf][key * 64 + ((4 + quad) ^ (key & 7)) * 8];
#pragma unroll
      for (int mq = 0; mq < 2; mq++) {
        s[mq][nk] = __builtin_amdgcn_mfma_f32_16x16x32_bf16(kf0, qf[mq][0], vz, 0, 0, 0);
        s[mq][nk] = __builtin_amdgcn_mfma_f32_16x16x32_bf16(kf1, qf[mq][1], s[mq][nk], 0, 0, 0);
      }
    }
    __builtin_amdgcn_s_setprio(0);

    // p = 2^s, packed fully in-register into PV A-fragments.
    // frag element j: k'-slot quad*8+j <-> orig key (2c+(j>>2))*16 + 4*quad + (j&3);
    // V staging permutation matches (gemm_bt OUTMODE=2).
    bf16x8 pa[2][2];
#pragma unroll
    for (int mq = 0; mq < 2; mq++)
#pragma unroll
      for (int c = 0; c < 2; c++) {
        union { uint_t u[4]; bf16x8 v; } pk;
#pragma unroll
        for (int t = 0; t < 4; t++) {
          float lo = EXP2(s[mq][2 * c + (t >> 1)][(t & 1) * 2 + 0]);
          float hi = EXP2(s[mq][2 * c + (t >> 1)][(t & 1) * 2 + 1]);
          uint_t w32;
          asm("v_cvt_pk_bf16_f32 %0, %1, %2" : "=v"(w32) : "v"(lo), "v"(hi));
          pk.u[t] = w32;
        }
        pa[mq][c] = pk.v;
      }

    __builtin_amdgcn_s_setprio(1);
#pragma unroll
    for (int c = 0; c < 2; c++)
#pragma unroll
      for (int mq = 0; mq < 2; mq++)
        lsum[mq] = __builtin_amdgcn_mfma_f32_16x16x32_bf16(pa[mq][c], onesf, lsum[mq], 0, 0, 0);
#pragma unroll
    for (int c = 0; c < 2; c++)
#pragma unroll
      for (int nd = 0; nd < 4; nd++) {
        bf16x8 vf = *(const bf16x8*)&sV[buf][(nd * 16 + l16) * 64 + ((c * 4 + quad) ^ xsw) * 8];
#pragma unroll
        for (int mq = 0; mq < 2; mq++)
          oacc[mq][nd] = __builtin_amdgcn_mfma_f32_16x16x32_bf16(pa[mq][c], vf, oacc[mq][nd], 0, 0, 0);
      }
    __builtin_amdgcn_s_setprio(0);
  }

  // epilogue: O / l -> attnout[b*T + q][h*64 + d]
  const int b = bh / NH, h = bh - b * NH;
#pragma unroll
  for (int mq = 0; mq < 2; mq++) {
    float inv[4];
#pragma unroll
    for (int r = 0; r < 4; r++) inv[r] = __builtin_amdgcn_rcpf(lsum[mq][r]);
#pragma unroll
    for (int nd = 0; nd < 4; nd++) {
#pragma unroll
      for (int r = 0; r < 4; r++) {
        size_t row = (size_t)b * TLEN + qt * 128 + w * 32 + mq * 16 + quad * 4 + r;
        int col = h * DH + nd * 16 + l16;
        attnout[row * DM + col] = f2b(oacc[mq][nd][r] * inv[r]);
      }
    }
  }
}

// ---------------- launcher ----------------
extern "C" void kernel_launch(void* const* d_in, const int* in_sizes, int n_in,
                              void* d_out, int out_size, void* d_ws, size_t ws_size,
                              hipStream_t stream) {
  const void* x_r = d_in[0];
  const void* ln1_g_r = d_in[1];
  const void* ln1_b_r = d_in[2];
  const void* qkv_w_r = d_in[3];
  const void* qkv_b_r = d_in[4];
  const void* ao_w_r = d_in[5];
  const void* ao_b_r = d_in[6];
  const void* ln2_g_r = d_in[7];
  const void* ln2_b_r = d_in[8];
  const void* ff1_w_r = d_in[9];
  const void* ff1_b_r = d_in[10];
  const void* ff2_w_r = d_in[11];
  const void* ff2_b_r = d_in[12];

  int* flag = (int*)d_ws;
  ushort_t* base = (ushort_t*)d_ws + 128;
  const size_t RD = STG;  // 6.29M el

  const size_t elA = RD + RD + (size_t)NROWS * DFF + RD + (size_t)DM * DM + 9984;
  const bool pathA = ws_size >= elA * 2 + 4096;

  detect_dtype<<<1, 256, 0, stream>>>((const ushort_t*)x_r, flag);

  if (pathA) {
    ushort_t* x2   = base;
    ushort_t* h    = base + RD;                    // h1 then h2
    ushort_t* big  = base + 2 * RD;                // staged qkv (18.87M) then ffb (25.17M)
    ushort_t* aux  = big + (size_t)NROWS * DFF;    // wTq | attnb | wT2+wT3
    ushort_t* wTa  = aux + RD;                     // [768][768]
    ushort_t* smalls = wTa + (size_t)DM * DM;
    ushort_t* wTq = aux;
    ushort_t* attnb = aux;
    ushort_t* wT2 = aux;
    ushort_t* wT3 = aux + (size_t)DFF * DM;
    ushort_t *g1 = smalls, *b1 = smalls + 768, *qb = smalls + 1536, *ab = smalls + 3840,
             *g2 = smalls + 4608, *b2 = smalls + 5376, *f1b = smalls + 6144, *f2bb = smalls + 9216;

    cvt_smalls<<<39, 256, 0, stream>>>(ln1_g_r, ln1_b_r, qkv_b_r, ao_b_r,
                                       ln2_g_r, ln2_b_r, ff1_b_r, ff2_b_r, smalls, flag);
    ln_kernel<true><<<NROWS / 4, 256, 0, stream>>>(x_r, g1, b1, h, flag);
    transpose_adapt<<<dim3(QKVW / 32, DM / 32), 256, 0, stream>>>(qkv_w_r, 0, wTq, DM, QKVW, QKVW, flag);
    gemm_bt<false, 0, 2, 64, 64><<<dim3(NROWS / 64, QKVW / 128), 256, 0, stream>>>(
        h, wTq, qb, nullptr, big, NROWS, QKVW, DM, 0, flag);
    attn_kernel<<<dim3(NH * BATCH, 16), 256, 0, stream>>>(big, big + STG, big + 2 * STG, attnb);
    transpose_adapt<<<dim3(DM / 32, DM / 32), 256, 0, stream>>>(ao_w_r, 0, wTa, DM, DM, DM, flag);
    gemm_bt<false, 2, 0, 64, 64><<<dim3(NROWS / 64, DM / 128), 256, 0, stream>>>(
        attnb, wTa, ab, x_r, x2, NROWS, DM, DM, 0, flag);
    ln_kernel<false><<<NROWS / 4, 256, 0, stream>>>(x2, g2, b2, h, flag);
    transpose_adapt<<<dim3(DFF / 32, DM / 32), 256, 0, stream>>>(ff1_w_r, 0, wT2, DM, DFF, DFF, flag);
    gemm_bt<true, 0, 0, 64, 64><<<dim3(NROWS / 64, DFF / 128), 256, 0, stream>>>(
        h, wT2, f1b, nullptr, big, NROWS, DFF, DM, 0, flag);
    transpose_adapt<<<dim3(DM / 32, DFF / 32), 256, 0, stream>>>(ff2_w_r, 0, wT3, DFF, DM, DM, flag);
    gemm_bt<false, 1, 1, 64, 64><<<dim3(NROWS / 64, DM / 128), 256, 0, stream>>>(
        big, wT3, f2bb, x2, d_out, NROWS, DM, DFF, 0, flag);
  } else {
    // 55.1 MB layout; FF in two 1536-wide slices
    ushort_t* regA = base;                                   // h / attnb / h2
    ushort_t* regB = base + RD;                              // staged qkv -> [x2 | ffq]
    ushort_t* slots = regB + (size_t)NROWS * QKVW;
    ushort_t* smalls = slots + (size_t)QKVW * DM + (size_t)DM * DM;
    ushort_t* h = regA, *attnb = regA, *h2 = regA;
    ushort_t* x2 = regB;
    ushort_t* ffq = regB + RD;                               // [8192][1536]
    ushort_t* wTq = slots;
    ushort_t* wTa = slots + (size_t)QKVW * DM;
    ushort_t* wT2 = slots;                                   // [1536][768]
    ushort_t* wT3 = slots + (size_t)1536 * DM;               // [768][1536]
    ushort_t *g1 = smalls, *b1 = smalls + 768, *qb = smalls + 1536, *ab = smalls + 3840,
             *g2 = smalls + 4608, *b2 = smalls + 5376, *f1b = smalls + 6144, *f2bb = smalls + 9216;

    cvt_smalls<<<39, 256, 0, stream>>>(ln1_g_r, ln1_b_r, qkv_b_r, ao_b_r,
                                       ln2_g_r, ln2_b_r, ff1_b_r, ff2_b_r, smalls, flag);
    ln_kernel<true><<<NROWS / 4, 256, 0, stream>>>(x_r, g1, b1, h, flag);
    transpose_adapt<<<dim3(QKVW / 32, DM / 32), 256, 0, stream>>>(qkv_w_r, 0, wTq, DM, QKVW, QKVW, flag);
    gemm_bt<false, 0, 2, 64, 64><<<dim3(NROWS / 64, QKVW / 128), 256, 0, stream>>>(
        h, wTq, qb, nullptr, regB, NROWS, QKVW, DM, 0, flag);
    attn_kernel<<<dim3(NH * BATCH, 16), 256, 0, stream>>>(regB, regB + STG, regB + 2 * STG, attnb);
    transpose_adapt<<<dim3(DM / 32, DM / 32), 256, 0, stream>>>(ao_w_r, 0, wTa, DM, DM, DM, flag);
    gemm_bt<false, 2, 0, 64, 64><<<dim3(NROWS / 64, DM / 128), 256, 0, stream>>>(
        attnb, wTa, ab, x_r, x2, NROWS, DM, DM, 0, flag);
    ln_kernel<false><<<NROWS / 4, 256, 0, stream>>>(x2, g2, b2, h2, flag);
    for (int q = 0; q < 2; q++) {
      transpose_adapt<<<dim3(1536 / 32, DM / 32), 256, 0, stream>>>(
          ff1_w_r, (long long)q * 1536, wT2, DM, 1536, DFF, flag);
      gemm_bt<true, 0, 0, 64, 64><<<dim3(NROWS / 64, 1536 / 128), 256, 0, stream>>>(
          h2, wT2, f1b + q * 1536, nullptr, ffq, NROWS, 1536, DM, 0, flag);
      transpose_adapt<<<dim3(DM / 32, 1536 / 32), 256, 0, stream>>>(
          ff2_w_r, (long long)q * 1536 * DM, wT3, 1536, DM, DM, flag);
      if (q == 0)
        gemm_bt<false, 1, 1, 64, 64><<<dim3(NROWS / 64, DM / 128), 256, 0, stream>>>(
            ffq, wT3, f2bb, x2, d_out, NROWS, DM, 1536, 0, flag);
      else
        gemm_bt<false, 0, 1, 64, 64><<<dim3(NROWS / 64, DM / 128), 256, 0, stream>>>(
            ffq, wT3, nullptr, nullptr, d_out, NROWS, DM, 1536, 1, flag);
    }
  }
}